// Round 6
// baseline (278.260 us; speedup 1.0000x reference)
//
#include <hip/hip_runtime.h>
#include <hip/hip_bf16.h>

// Performer (FAVOR+) attention. B=4 H=8 N=4096 D=64 M=256.
// Round-12:
//  - kside: round-11 T14 prefetch version VALIDATED (97->73us, no spills).
//    Untouched this round.
//  - out_kernel: apply the SAME T14 register-prefetch to its mc-loop staging.
//    Was {barrier -> L2 loads of sP/sC -> LDS write -> barrier -> MFMA}:
//    staging latency serialized inside the barrier pair at 2 blocks/CU.
//    Now: hold mc+1's 8x uint4 staging in regs (+32 VGPR, cap 256 @ (256,2)
//    -> no spill), ds_write at loop-top barrier, issue mc+1 loads right
//    after the write-barrier -> whole MFMA phase (~28 MFMAs + exp) hides
//    the L2 latency. LDS double-buffer impossible (79KB already).

typedef __attribute__((ext_vector_type(8))) short short8;
typedef __attribute__((ext_vector_type(4))) float floatx4;

constexpr int BB = 4, HH = 8, NN = 4096, DD = 64, MM = 256, BH = 32;
constexpr int NCH = 16;  // n-chunks per head (kside grid.x)
constexpr float SCALE = 0.3535533905932738f;  // 64^-0.25
constexpr float RATIO = 0.0625f;              // 256^-0.5
constexpr float EPSI  = 1e-4f;
constexpr float NEGINF = -3.4e38f;

__device__ inline unsigned pk2(float a, float b) {
  unsigned ua = __float_as_uint(a) + 0x8000u;
  unsigned ub = __float_as_uint(b) + 0x8000u;
  return (ua >> 16) | (ub & 0xffff0000u);
}
__device__ inline float hif(float x) {
  return __uint_as_float((__float_as_uint(x) + 0x8000u) & 0xffff0000u);
}
__device__ inline unsigned short bhi(float x) {
  return (unsigned short)((__float_as_uint(x) + 0x8000u) >> 16);
}
__device__ inline int ph16(int i) { return (i & 56) | ((i + (i >> 3)) & 7); }

union Frag { short8 s8; unsigned u[4]; };

__device__ inline void atomicMaxF(float* a, float v) {
  unsigned* ai = (unsigned*)a;
  unsigned old = __atomic_load_n(ai, __ATOMIC_RELAXED);
  while (__uint_as_float(old) < v) {
    unsigned assumed = old;
    old = atomicCAS(ai, assumed, __float_as_uint(v));
    if (old == assumed) break;
  }
}

// ---------------- prep: split proj; init stabk; zero small accumulators ----
__global__ __launch_bounds__(256) void prep_kernel(
    const float* __restrict__ proj, unsigned short* __restrict__ projH,
    unsigned short* __restrict__ projL, float* __restrict__ stabk,
    float* __restrict__ Vs, float* __restrict__ ctxsum,
    float* __restrict__ ksE) {
  const int i = blockIdx.x * 256 + threadIdx.x;  // 16384 elems
  float v = proj[i];
  projH[i] = bhi(v);
  projL[i] = bhi(v - hif(v));
  if (i < BH) stabk[i] = NEGINF;
  if (i < 2048) { Vs[i] = 0.f; ctxsum[i] = 0.f; }
  if (i < 8192) ksE[i] = 0.f;
}

// ---------------- kside: MFMA phi_k pass (round-11 verbatim) ---------------
// grid (NCH, 32), 256 thr. Block: 256 K-rows, 8 chunks of 32, all 256 feats.
// T14 prefetch: chunk ch+1's K/V loads issued post-staging-barrier.
template <bool PARTIAL>
__global__ __launch_bounds__(256) void kside_kernel(
    const float* __restrict__ K, const float* __restrict__ V,
    const float* __restrict__ mask,
    const unsigned short* __restrict__ projH, const unsigned short* __restrict__ projL,
    float* __restrict__ stabk, float* __restrict__ ksE,
    float* __restrict__ ctxOut, float* __restrict__ Vs) {
  const int bh = blockIdx.y, b = bh >> 3;
  const int t = threadIdx.x;
  const int w = t >> 6, l = t & 63, c = l & 15, sq = l >> 4;
  const int m0 = w * 64;

  __shared__ __align__(16) unsigned short sK[2][32 * 72];   // [plane][n][d] pad 72
  __shared__ __align__(16) unsigned short sVt[2][64 * 40];  // [plane][e][n] pad 40
  __shared__ float sDiag[32];
  __shared__ float sRed[4];
  __shared__ float sVsum[4][64];
  __shared__ __align__(16) unsigned short sPhi[4][2][512];  // [w][plane][swizzled]

  // persistent B-frags of P^T from pre-split planes
  Frag Bp[4][2][2];
#pragma unroll
  for (int tt = 0; tt < 4; ++tt)
#pragma unroll
    for (int s = 0; s < 2; ++s) {
      const size_t o = (size_t)(m0 + tt * 16 + c) * DD + s * 32 + sq * 8;
      Bp[tt][s][0].s8 = *(const short8*)&projH[o];
      Bp[tt][s][1].s8 = *(const short8*)&projL[o];
    }

  floatx4 ctxacc[4][4];
#pragma unroll
  for (int i = 0; i < 4; ++i)
#pragma unroll
    for (int j = 0; j < 4; ++j) ctxacc[i][j] = (floatx4){0.f, 0.f, 0.f, 0.f};
  float ksac[4] = {0.f, 0.f, 0.f, 0.f};
  float mxloc = NEGINF;
  float vsacc = 0.f;  // masked V column-sum partial (column estar = c*4+sq)

  const int r0 = blockIdx.x * 256;

  // ---- prime prefetch for ch=0 ----
  float4 pk4[2], pv4[2];
  float pmk[2], pmv[2];
  {
    const int rb = r0;
#pragma unroll
    for (int rep = 0; rep < 2; ++rep) {
      const int f = t + rep * 256;
      const int n = f >> 4;
      pmk[rep] = mask[b * NN + rb + n];
      pk4[rep] = *(const float4*)(K + ((size_t)bh * NN + rb + n) * DD + (f & 15) * 4);
      const int n_loc = w * 4 + rep * 16 + sq;
      pmv[rep] = mask[b * NN + rb + n_loc];
      pv4[rep] = *(const float4*)(V + ((size_t)bh * NN + rb + n_loc) * DD + c * 4);
    }
  }

  for (int ch = 0; ch < 8; ++ch) {
    __syncthreads();

    // ---- stage K (scaled+masked, split) + diag, from prefetched regs ----
#pragma unroll
    for (int rep = 0; rep < 2; ++rep) {
      const int f = t + rep * 256;
      const int n = f >> 4, dg = f & 15;
      const float msc = pmk[rep] * SCALE;
      float k0 = pk4[rep].x * msc, k1 = pk4[rep].y * msc,
            k2 = pk4[rep].z * msc, k3 = pk4[rep].w * msc;
      float ss = fmaf(k0, k0, fmaf(k1, k1, fmaf(k2, k2, k3 * k3)));
      ss += __shfl_xor(ss, 1); ss += __shfl_xor(ss, 2);
      ss += __shfl_xor(ss, 4); ss += __shfl_xor(ss, 8);
      if (dg == 0) sDiag[n] = 0.5f * ss;
      unsigned h0 = pk2(k0, k1), h1 = pk2(k2, k3);
      float q0 = k0 - hif(k0), q1 = k1 - hif(k1);
      float q2 = k2 - hif(k2), q3 = k3 - hif(k3);
      *(uint2*)(&sK[0][n * 72 + dg * 4]) = make_uint2(h0, h1);
      *(uint2*)(&sK[1][n * 72 + dg * 4]) = make_uint2(pk2(q0, q1), pk2(q2, q3));
    }

    // ---- stage V^T via wave shfl-transpose; accumulate Vs partial ----
#pragma unroll
    for (int rep = 0; rep < 2; ++rep) {
      const int nb = w * 4 + rep * 16;
      const float mk = pmv[rep];
      float4 vv = pv4[rep];
      float va[4] = {vv.x * mk, vv.y * mk, vv.z * mk, vv.w * mk};
      float g[4];
#pragma unroll
      for (int k = 0; k < 4; ++k) {
        const int gi = (sq + k) & 3;
        float sel = va[(sq - k) & 3];
        g[gi] = __shfl(sel, gi * 16 + c);
      }
      const int estar = c * 4 + sq;  // lane's column, rows nb..nb+3
      vsacc += ((g[0] + g[1]) + (g[2] + g[3]));
      unsigned h0 = pk2(g[0], g[1]), h1 = pk2(g[2], g[3]);
      float q0 = g[0] - hif(g[0]), q1 = g[1] - hif(g[1]);
      float q2 = g[2] - hif(g[2]), q3 = g[3] - hif(g[3]);
      *(uint2*)(&sVt[0][estar * 40 + nb]) = make_uint2(h0, h1);
      *(uint2*)(&sVt[1][estar * 40 + nb]) = make_uint2(pk2(q0, q1), pk2(q2, q3));
    }
    __syncthreads();

    // ---- issue next chunk's loads: whole MFMA phase hides the latency ----
    if (ch < 7) {
      const int rb = r0 + (ch + 1) * 32;
#pragma unroll
      for (int rep = 0; rep < 2; ++rep) {
        const int f = t + rep * 256;
        const int n = f >> 4;
        pmk[rep] = mask[b * NN + rb + n];
        pk4[rep] = *(const float4*)(K + ((size_t)bh * NN + rb + n) * DD + (f & 15) * 4);
        const int n_loc = w * 4 + rep * 16 + sq;
        pmv[rep] = mask[b * NN + rb + n_loc];
        pv4[rep] = *(const float4*)(V + ((size_t)bh * NN + rb + n_loc) * DD + c * 4);
      }
    }

    // ---- frags ----
    Frag Ak[2][2][2];
#pragma unroll
    for (int i = 0; i < 2; ++i)
#pragma unroll
      for (int s = 0; s < 2; ++s) {
        Ak[i][s][0].s8 = *(const short8*)&sK[0][(i * 16 + c) * 72 + s * 32 + sq * 8];
        Ak[i][s][1].s8 = *(const short8*)&sK[1][(i * 16 + c) * 72 + s * 32 + sq * 8];
      }
    Frag Bv[4][2];
#pragma unroll
    for (int E = 0; E < 4; ++E) {
      Bv[E][0].s8 = *(const short8*)&sVt[0][(E * 16 + c) * 40 + sq * 8];
      Bv[E][1].s8 = *(const short8*)&sVt[1][(E * 16 + c) * 40 + sq * 8];
    }

#pragma unroll
    for (int tt = 0; tt < 4; ++tt) {
      // S1: xp for both n-tiles
      floatx4 xacc[2];
#pragma unroll
      for (int i = 0; i < 2; ++i) {
        floatx4 a = (floatx4){0.f, 0.f, 0.f, 0.f};
#pragma unroll
        for (int s = 0; s < 2; ++s) {
          a = __builtin_amdgcn_mfma_f32_16x16x32_bf16(Ak[i][s][0].s8, Bp[tt][s][0].s8, a, 0, 0, 0);
          a = __builtin_amdgcn_mfma_f32_16x16x32_bf16(Ak[i][s][0].s8, Bp[tt][s][1].s8, a, 0, 0, 0);
          a = __builtin_amdgcn_mfma_f32_16x16x32_bf16(Ak[i][s][1].s8, Bp[tt][s][0].s8, a, 0, 0, 0);
        }
        xacc[i] = a;
      }
      // S2: exp frame-0, max, ksum, phi scatter (wave-local, swizzled)
      const int qp_c = sq >> 1, half = (sq & 1) * 4;
#pragma unroll
      for (int i = 0; i < 2; ++i) {
        float p[4];
#pragma unroll
        for (int jj = 0; jj < 4; ++jj) {
          float xp = xacc[i][jj];
          mxloc = fmaxf(mxloc, xp);
          p[jj] = __expf(xp - sDiag[i * 16 + sq * 4 + jj]);
          ksac[tt] += p[jj];
        }
        unsigned h0 = pk2(p[0], p[1]), h1 = pk2(p[2], p[3]);
        float q0 = p[0] - hif(p[0]), q1 = p[1] - hif(p[1]);
        float q2 = p[2] - hif(p[2]), q3 = p[3] - hif(p[3]);
        const int tl = (i * 2 + qp_c) * 16 + c;
        const int idx = ph16(tl) * 8 + half;
        *(uint2*)&sPhi[w][0][idx] = make_uint2(h0, h1);
        *(uint2*)&sPhi[w][1][idx] = make_uint2(pk2(q0, q1), pk2(q2, q3));
      }
      // S3: ctx += phi^T @ Vm (wave-local DS ordering: no barrier needed)
      Frag Ap[2];
      Ap[0].s8 = *(const short8*)&sPhi[w][0][ph16(l) * 8];
      Ap[1].s8 = *(const short8*)&sPhi[w][1][ph16(l) * 8];
#pragma unroll
      for (int E = 0; E < 4; ++E) {
        ctxacc[tt][E] = __builtin_amdgcn_mfma_f32_16x16x32_bf16(Ap[0].s8, Bv[E][0].s8, ctxacc[tt][E], 0, 0, 0);
        ctxacc[tt][E] = __builtin_amdgcn_mfma_f32_16x16x32_bf16(Ap[0].s8, Bv[E][1].s8, ctxacc[tt][E], 0, 0, 0);
        ctxacc[tt][E] = __builtin_amdgcn_mfma_f32_16x16x32_bf16(Ap[1].s8, Bv[E][0].s8, ctxacc[tt][E], 0, 0, 0);
      }
    }
  }

  // ---- epilogue: ksum partials, block max, Vs partial, ctx out ----
#pragma unroll
  for (int tt = 0; tt < 4; ++tt) {
    float v = ksac[tt];
    v += __shfl_xor(v, 16);
    v += __shfl_xor(v, 32);
    if (sq == 0) atomicAdd(&ksE[bh * MM + m0 + tt * 16 + c], v);
  }
#pragma unroll
  for (int off = 1; off <= 32; off <<= 1) mxloc = fmaxf(mxloc, __shfl_xor(mxloc, off));
  if (l == 0) sRed[w] = mxloc;
  sVsum[w][c * 4 + sq] = vsacc;
  __syncthreads();
  if (t == 0)
    atomicMaxF(&stabk[bh], fmaxf(fmaxf(sRed[0], sRed[1]), fmaxf(sRed[2], sRed[3])));
  if (t < 64)
    atomicAdd(&Vs[bh * DD + t],
              (sVsum[0][t] + sVsum[1][t]) + (sVsum[2][t] + sVsum[3][t]));

  if (PARTIAL) {
    float* cg = ctxOut + ((size_t)(bh * NCH + blockIdx.x) * MM) * DD;
#pragma unroll
    for (int tt = 0; tt < 4; ++tt)
#pragma unroll
      for (int E = 0; E < 4; ++E)
#pragma unroll
        for (int r = 0; r < 4; ++r)
          cg[(m0 + tt * 16 + sq * 4 + r) * DD + E * 16 + c] = ctxacc[tt][E][r];
  } else {
    float* cg = ctxOut + (size_t)bh * MM * DD;
#pragma unroll
    for (int tt = 0; tt < 4; ++tt)
#pragma unroll
      for (int E = 0; E < 4; ++E)
#pragma unroll
        for (int r = 0; r < 4; ++r)
          atomicAdd(&cg[(m0 + tt * 16 + sq * 4 + r) * DD + E * 16 + c],
                    ctxacc[tt][E][r]);
  }
}

// ---------------- fixup: reduce partials, scale+eps, emit ctxT; ksfin ------
// grid (8 mchunks of 32, 32 bh), 256 thr.
template <int NPARTS>
__global__ __launch_bounds__(256) void fixup_kernel(
    const float* __restrict__ stabk, const float* __restrict__ Vs,
    const float* __restrict__ ksE, const float* __restrict__ ctxParts,
    float* __restrict__ ksum, float* __restrict__ kssum,
    float* __restrict__ ctxsum, unsigned short* __restrict__ ctxTH,
    unsigned short* __restrict__ ctxTL) {
  const int bh = blockIdx.y, mc = blockIdx.x, t = threadIdx.x;
  const float es = __expf(-stabk[bh]);
  const int e = t & 63, g = t >> 6;
  const float vse = EPSI * Vs[bh * DD + e];

  __shared__ float tile[64 * 33];  // [e][ml] ml<32
  __shared__ float cred[256];

  float csum = 0.f;
#pragma unroll
  for (int r = 0; r < 8; ++r) {
    const int ml = r * 4 + g;        // m-local in 32-chunk
    const int m = mc * 32 + ml;
    float x = 0.f;
#pragma unroll
    for (int p = 0; p < NPARTS; ++p)
      x += ctxParts[(((size_t)bh * NPARTS + p) * MM + m) * DD + e];
    float v = RATIO * (es * x + vse);
    csum += v;
    tile[e * 33 + ml] = v;
  }
  cred[t] = csum;
  __syncthreads();
  if (t < 64)
    atomicAdd(&ctxsum[bh * DD + t],
              (cred[t] + cred[t + 64]) + (cred[t + 128] + cred[t + 192]));

  // coalesced transposed write-out
  {
    const int ml5 = t & 31, elg = t >> 5;
#pragma unroll
    for (int r = 0; r < 8; ++r) {
      const int el = r * 8 + elg;
      float v = tile[el * 33 + ml5];
      const size_t o = ((size_t)(bh * DD + el)) * MM + mc * 32 + ml5;
      ctxTH[o] = bhi(v);
      ctxTL[o] = bhi(v - hif(v));
    }
  }

  // ksfin fold (one block column per head)
  if (mc == 0) {
    __syncthreads();
    const float kv = RATIO * (es * ksE[bh * MM + t] + (float)NN * EPSI);
    ksum[bh * MM + t] = kv;
    cred[t] = kv;
    __syncthreads();
    for (int off = 128; off >= 1; off >>= 1) {
      if (t < off) cred[t] += cred[t + off];
      __syncthreads();
    }
    if (t == 0) kssum[bh] = cred[0];
  }
}

// ---------------- out: MFMA Q side + T14 staging prefetch ------------------
__global__ __launch_bounds__(256, 2) void out_kernel(
    const float* __restrict__ Q,
    const unsigned short* __restrict__ projH, const unsigned short* __restrict__ projL,
    const float* __restrict__ ksum,
    const unsigned short* __restrict__ ctxTH, const unsigned short* __restrict__ ctxTL,
    const float* __restrict__ kssum, const float* __restrict__ ctxsum,
    float* __restrict__ out) {
  const int bh = blockIdx.y;
  const int r0 = blockIdx.x * 64;
  const int t = threadIdx.x, w = t >> 6, l = t & 63, c = l & 15, sq = l >> 4;
  const int row = t >> 2, q4 = t & 3;

  __shared__ __align__(16) unsigned short sQ[2][64 * 80];
  __shared__ __align__(16) unsigned short sP[2][64 * 80];
  __shared__ __align__(16) unsigned short sC[2][64 * 80];
  __shared__ float sKs[256];
  __shared__ float sDiag[64];
  __shared__ __align__(16) unsigned short sPhi[4][2][2][512];

  {
    const float* qp = Q + ((size_t)bh * NN + r0 + row) * DD + q4 * 16;
    float4 t0 = *(const float4*)(qp + 0), t1 = *(const float4*)(qp + 4),
           t2 = *(const float4*)(qp + 8), t3 = *(const float4*)(qp + 12);
    float v[16] = {t0.x, t0.y, t0.z, t0.w, t1.x, t1.y, t1.z, t1.w,
                   t2.x, t2.y, t2.z, t2.w, t3.x, t3.y, t3.z, t3.w};
    float ss = 0.f;
#pragma unroll
    for (int j = 0; j < 16; ++j) { v[j] *= SCALE; ss = fmaf(v[j], v[j], ss); }
    ss += __shfl_xor(ss, 1);
    ss += __shfl_xor(ss, 2);
    if (q4 == 0) sDiag[row] = 0.5f * ss;
    unsigned short* dh = &sQ[0][row * 80 + q4 * 16];
    unsigned short* dl = &sQ[1][row * 80 + q4 * 16];
#pragma unroll
    for (int j = 0; j < 8; ++j) {
      *(unsigned*)&dh[2 * j] = pk2(v[2 * j], v[2 * j + 1]);
      float l0 = v[2 * j] - hif(v[2 * j]), l1 = v[2 * j + 1] - hif(v[2 * j + 1]);
      *(unsigned*)&dl[2 * j] = pk2(l0, l1);
    }
  }
  sKs[t] = ksum[bh * MM + t];

  // ---- prime staging prefetch for mc=0 (regs; consumed at loop-top) ----
  uint4 pfP[4], pfC[4];
  {
    const size_t gp = (size_t)(row)*DD + q4 * 16;
    pfP[0] = ((const uint4*)&projH[gp])[0];
    pfP[1] = ((const uint4*)&projH[gp])[1];
    pfP[2] = ((const uint4*)&projL[gp])[0];
    pfP[3] = ((const uint4*)&projL[gp])[1];
    const size_t gc = ((size_t)bh * DD + row) * MM + q4 * 16;
    pfC[0] = ((const uint4*)&ctxTH[gc])[0];
    pfC[1] = ((const uint4*)&ctxTH[gc])[1];
    pfC[2] = ((const uint4*)&ctxTL[gc])[0];
    pfC[3] = ((const uint4*)&ctxTL[gc])[1];
  }
  __syncthreads();

  Frag Bq[2][2];
#pragma unroll
  for (int s = 0; s < 2; ++s)
#pragma unroll
    for (int p = 0; p < 2; ++p)
      Bq[s][p].s8 = *(const short8*)&sQ[p][(w * 16 + c) * 80 + s * 32 + sq * 8];

  const float diagc = sDiag[w * 16 + c];
  floatx4 oacc[4];
#pragma unroll
  for (int E = 0; E < 4; ++E) oacc[E] = (floatx4){0.f, 0.f, 0.f, 0.f};
  float mxacc = NEGINF, dsacc = 0.f;

  for (int mc = 0; mc < 4; ++mc) {
    __syncthreads();
    // ---- write prefetched staging regs to LDS ----
    {
      *(uint4*)&sP[0][row * 80 + q4 * 16] = pfP[0];
      *(uint4*)&sP[0][row * 80 + q4 * 16 + 8] = pfP[1];
      *(uint4*)&sP[1][row * 80 + q4 * 16] = pfP[2];
      *(uint4*)&sP[1][row * 80 + q4 * 16 + 8] = pfP[3];
      *(uint4*)&sC[0][row * 80 + q4 * 16] = pfC[0];
      *(uint4*)&sC[0][row * 80 + q4 * 16 + 8] = pfC[1];
      *(uint4*)&sC[1][row * 80 + q4 * 16] = pfC[2];
      *(uint4*)&sC[1][row * 80 + q4 * 16 + 8] = pfC[3];
    }
    __syncthreads();

    // ---- issue mc+1 staging loads: MFMA phase below hides L2 latency ----
    if (mc < 3) {
      const size_t gp = (size_t)((mc + 1) * 64 + row) * DD + q4 * 16;
      pfP[0] = ((const uint4*)&projH[gp])[0];
      pfP[1] = ((const uint4*)&projH[gp])[1];
      pfP[2] = ((const uint4*)&projL[gp])[0];
      pfP[3] = ((const uint4*)&projL[gp])[1];
      const size_t gc = ((size_t)bh * DD + row) * MM + (mc + 1) * 64 + q4 * 16;
      pfC[0] = ((const uint4*)&ctxTH[gc])[0];
      pfC[1] = ((const uint4*)&ctxTH[gc])[1];
      pfC[2] = ((const uint4*)&ctxTL[gc])[0];
      pfC[3] = ((const uint4*)&ctxTL[gc])[1];
    }

#pragma unroll
    for (int tt = 0; tt < 4; ++tt) {
      Frag Af[2][2];
#pragma unroll
      for (int s = 0; s < 2; ++s)
#pragma unroll
        for (int p = 0; p < 2; ++p)
          Af[s][p].s8 = *(const short8*)&sP[p][(tt * 16 + c) * 80 + s * 32 + sq * 8];
      floatx4 x = (floatx4){0.f, 0.f, 0.f, 0.f};
#pragma unroll
      for (int s = 0; s < 2; ++s) {
        x = __builtin_amdgcn_mfma_f32_16x16x32_bf16(Af[s][0].s8, Bq[s][0].s8, x, 0, 0, 0);
        x = __builtin_amdgcn_mfma_f32_16x16x32_bf16(Af[s][0].s8, Bq[s][1].s8, x, 0, 0, 0);
        x = __builtin_amdgcn_mfma_f32_16x16x32_bf16(Af[s][1].s8, Bq[s][0].s8, x, 0, 0, 0);
      }
      float p4[4];
#pragma unroll
      for (int jj = 0; jj < 4; ++jj) {
        const float xp = x[jj];
        mxacc = fmaxf(mxacc, xp);
        p4[jj] = __expf(xp - diagc);
        dsacc = fmaf(p4[jj], sKs[mc * 64 + tt * 16 + sq * 4 + jj], dsacc);
      }
      const int kstep = tt >> 1;
      const int tl = ((tt & 1) * 2 + (sq >> 1)) * 16 + c;
      const int off = (sq & 1) * 4;
      float l0 = p4[0] - hif(p4[0]), l1 = p4[1] - hif(p4[1]);
      float l2 = p4[2] - hif(p4[2]), l3 = p4[3] - hif(p4[3]);
      *(uint2*)&sPhi[w][0][kstep][tl * 8 + off] = make_uint2(pk2(p4[0], p4[1]), pk2(p4[2], p4[3]));
      *(uint2*)&sPhi[w][1][kstep][tl * 8 + off] = make_uint2(pk2(l0, l1), pk2(l2, l3));
    }

#pragma unroll
    for (int ks = 0; ks < 2; ++ks) {
      Frag Aph[2];
      Aph[0].s8 = *(const short8*)&sPhi[w][0][ks][l * 8];
      Aph[1].s8 = *(const short8*)&sPhi[w][1][ks][l * 8];
#pragma unroll
      for (int E = 0; E < 4; ++E) {
        Frag Bc0, Bc1;
        Bc0.s8 = *(const short8*)&sC[0][(E * 16 + c) * 80 + ks * 32 + sq * 8];
        Bc1.s8 = *(const short8*)&sC[1][(E * 16 + c) * 80 + ks * 32 + sq * 8];
        oacc[E] = __builtin_amdgcn_mfma_f32_16x16x32_bf16(Aph[0].s8, Bc0.s8, oacc[E], 0, 0, 0);
        oacc[E] = __builtin_amdgcn_mfma_f32_16x16x32_bf16(Aph[0].s8, Bc1.s8, oacc[E], 0, 0, 0);
        oacc[E] = __builtin_amdgcn_mfma_f32_16x16x32_bf16(Aph[1].s8, Bc0.s8, oacc[E], 0, 0, 0);
      }
    }
  }

  mxacc = fmaxf(mxacc, __shfl_xor(mxacc, 16));
  mxacc = fmaxf(mxacc, __shfl_xor(mxacc, 32));
  dsacc += __shfl_xor(dsacc, 16);
  dsacc += __shfl_xor(dsacc, 32);

  const float kss = kssum[bh];
  float fac[4], oinv[4];
#pragma unroll
  for (int jj = 0; jj < 4; ++jj) {
    const int src = sq * 4 + jj;
    const float s_row = __shfl(mxacc, src);
    const float d_row = __shfl(dsacc, src);
    const float f = __expf(s_row) * EPSI;
    fac[jj] = f;
    oinv[jj] = 1.f / (d_row + f * kss);
  }

  const float* csb = ctxsum + bh * DD;
#pragma unroll
  for (int E = 0; E < 4; ++E) {
    const float cse = csb[E * 16 + c];
#pragma unroll
    for (int jj = 0; jj < 4; ++jj) {
      const int row2 = r0 + w * 16 + sq * 4 + jj;
      out[((size_t)bh * NN + row2) * DD + E * 16 + c] =
          (oacc[E][jj] + fac[jj] * cse) * oinv[jj];
    }
  }
}

extern "C" void kernel_launch(void* const* d_in, const int* in_sizes, int n_in,
                              void* d_out, int out_size, void* d_ws, size_t ws_size,
                              hipStream_t stream) {
  const float* Q    = (const float*)d_in[0];
  const float* K    = (const float*)d_in[1];
  const float* V    = (const float*)d_in[2];
  const float* mask = (const float*)d_in[3];
  const float* proj = (const float*)d_in[4];
  float* out = (float*)d_out;

  float* wsf = (float*)d_ws;
  float* stabk  = wsf;                          // 32
  float* ksum   = wsf + 32;                     // 8192
  float* kssum  = wsf + 8224;                   // 32
  float* Vs     = wsf + 8256;                   // 2048
  float* ctxsum = wsf + 10304;                  // 2048
  float* ksE    = wsf + 12352;                  // 8192
  unsigned short* projH = (unsigned short*)(wsf + 20544);   // 16384 shorts
  unsigned short* projL = (unsigned short*)(wsf + 28736);   // 16384 shorts
  unsigned short* ctxTH = (unsigned short*)(wsf + 36928);   // 524288 shorts
  unsigned short* ctxTL = (unsigned short*)(wsf + 299072);  // 524288 shorts
  float* ctxBig = wsf + 561216;  // PARTIAL: NCH*32*16384 = 8388608 fl (33.5MB)
                                 // fallback: 524288 fl (ctxE)

  const size_t need_partial = (size_t)(561216 + NCH * BH * MM * DD) * 4;
  const bool partial = ws_size >= need_partial;

  prep_kernel<<<64, 256, 0, stream>>>(proj, projH, projL, stabk, Vs, ctxsum, ksE);

  if (partial) {
    kside_kernel<true><<<dim3(NCH, BH), 256, 0, stream>>>(
        K, V, mask, projH, projL, stabk, ksE, ctxBig, Vs);
    fixup_kernel<NCH><<<dim3(8, BH), 256, 0, stream>>>(
        stabk, Vs, ksE, ctxBig, ksum, kssum, ctxsum, ctxTH, ctxTL);
  } else {
    hipMemsetAsync(ctxBig, 0, (size_t)MM * DD * BH * 4, stream);
    kside_kernel<false><<<dim3(NCH, BH), 256, 0, stream>>>(
        K, V, mask, projH, projL, stabk, ksE, ctxBig, Vs);
    fixup_kernel<1><<<dim3(8, BH), 256, 0, stream>>>(
        stabk, Vs, ksE, ctxBig, ksum, kssum, ctxsum, ctxTH, ctxTL);
  }

  out_kernel<<<dim3(64, BH), 256, 0, stream>>>(
      Q, projH, projL, ksum, ctxTH, ctxTL, kssum, ctxsum, out);
}

// Round 7
// 277.224 us; speedup vs baseline: 1.0037x; 1.0037x over previous
//
#include <hip/hip_runtime.h>
#include <hip/hip_bf16.h>

// Performer (FAVOR+) attention. B=4 H=8 N=4096 D=64 M=256.
// Round-13:
//  - Round-12 post-mortem: out_kernel's T14 prefetch spilled (WRITE_SIZE
//    33->182MB, VGPR 128->124) because __launch_bounds__(256,2) empirically
//    pins hipcc to ~128 VGPRs (r4:128, r12:124+spill) while plain (256)
//    allocates freely (r9:44, r10:144, kside r11:160 -- all spill-free).
//    out is LDS-capped at 2 blocks/CU (79KB) so the ,2 hint buys nothing.
//  - ONE change vs round-12: out_kernel __launch_bounds__(256,2) -> (256).
//    kside (r11 T14, validated 97->73us), fixup, prep byte-identical.

typedef __attribute__((ext_vector_type(8))) short short8;
typedef __attribute__((ext_vector_type(4))) float floatx4;

constexpr int BB = 4, HH = 8, NN = 4096, DD = 64, MM = 256, BH = 32;
constexpr int NCH = 16;  // n-chunks per head (kside grid.x)
constexpr float SCALE = 0.3535533905932738f;  // 64^-0.25
constexpr float RATIO = 0.0625f;              // 256^-0.5
constexpr float EPSI  = 1e-4f;
constexpr float NEGINF = -3.4e38f;

__device__ inline unsigned pk2(float a, float b) {
  unsigned ua = __float_as_uint(a) + 0x8000u;
  unsigned ub = __float_as_uint(b) + 0x8000u;
  return (ua >> 16) | (ub & 0xffff0000u);
}
__device__ inline float hif(float x) {
  return __uint_as_float((__float_as_uint(x) + 0x8000u) & 0xffff0000u);
}
__device__ inline unsigned short bhi(float x) {
  return (unsigned short)((__float_as_uint(x) + 0x8000u) >> 16);
}
__device__ inline int ph16(int i) { return (i & 56) | ((i + (i >> 3)) & 7); }

union Frag { short8 s8; unsigned u[4]; };

__device__ inline void atomicMaxF(float* a, float v) {
  unsigned* ai = (unsigned*)a;
  unsigned old = __atomic_load_n(ai, __ATOMIC_RELAXED);
  while (__uint_as_float(old) < v) {
    unsigned assumed = old;
    old = atomicCAS(ai, assumed, __float_as_uint(v));
    if (old == assumed) break;
  }
}

// ---------------- prep: split proj; init stabk; zero small accumulators ----
__global__ __launch_bounds__(256) void prep_kernel(
    const float* __restrict__ proj, unsigned short* __restrict__ projH,
    unsigned short* __restrict__ projL, float* __restrict__ stabk,
    float* __restrict__ Vs, float* __restrict__ ctxsum,
    float* __restrict__ ksE) {
  const int i = blockIdx.x * 256 + threadIdx.x;  // 16384 elems
  float v = proj[i];
  projH[i] = bhi(v);
  projL[i] = bhi(v - hif(v));
  if (i < BH) stabk[i] = NEGINF;
  if (i < 2048) { Vs[i] = 0.f; ctxsum[i] = 0.f; }
  if (i < 8192) ksE[i] = 0.f;
}

// ---------------- kside: MFMA phi_k pass (round-11 verbatim) ---------------
// grid (NCH, 32), 256 thr. Block: 256 K-rows, 8 chunks of 32, all 256 feats.
// T14 prefetch: chunk ch+1's K/V loads issued post-staging-barrier.
template <bool PARTIAL>
__global__ __launch_bounds__(256) void kside_kernel(
    const float* __restrict__ K, const float* __restrict__ V,
    const float* __restrict__ mask,
    const unsigned short* __restrict__ projH, const unsigned short* __restrict__ projL,
    float* __restrict__ stabk, float* __restrict__ ksE,
    float* __restrict__ ctxOut, float* __restrict__ Vs) {
  const int bh = blockIdx.y, b = bh >> 3;
  const int t = threadIdx.x;
  const int w = t >> 6, l = t & 63, c = l & 15, sq = l >> 4;
  const int m0 = w * 64;

  __shared__ __align__(16) unsigned short sK[2][32 * 72];   // [plane][n][d] pad 72
  __shared__ __align__(16) unsigned short sVt[2][64 * 40];  // [plane][e][n] pad 40
  __shared__ float sDiag[32];
  __shared__ float sRed[4];
  __shared__ float sVsum[4][64];
  __shared__ __align__(16) unsigned short sPhi[4][2][512];  // [w][plane][swizzled]

  // persistent B-frags of P^T from pre-split planes
  Frag Bp[4][2][2];
#pragma unroll
  for (int tt = 0; tt < 4; ++tt)
#pragma unroll
    for (int s = 0; s < 2; ++s) {
      const size_t o = (size_t)(m0 + tt * 16 + c) * DD + s * 32 + sq * 8;
      Bp[tt][s][0].s8 = *(const short8*)&projH[o];
      Bp[tt][s][1].s8 = *(const short8*)&projL[o];
    }

  floatx4 ctxacc[4][4];
#pragma unroll
  for (int i = 0; i < 4; ++i)
#pragma unroll
    for (int j = 0; j < 4; ++j) ctxacc[i][j] = (floatx4){0.f, 0.f, 0.f, 0.f};
  float ksac[4] = {0.f, 0.f, 0.f, 0.f};
  float mxloc = NEGINF;
  float vsacc = 0.f;  // masked V column-sum partial (column estar = c*4+sq)

  const int r0 = blockIdx.x * 256;

  // ---- prime prefetch for ch=0 ----
  float4 pk4[2], pv4[2];
  float pmk[2], pmv[2];
  {
    const int rb = r0;
#pragma unroll
    for (int rep = 0; rep < 2; ++rep) {
      const int f = t + rep * 256;
      const int n = f >> 4;
      pmk[rep] = mask[b * NN + rb + n];
      pk4[rep] = *(const float4*)(K + ((size_t)bh * NN + rb + n) * DD + (f & 15) * 4);
      const int n_loc = w * 4 + rep * 16 + sq;
      pmv[rep] = mask[b * NN + rb + n_loc];
      pv4[rep] = *(const float4*)(V + ((size_t)bh * NN + rb + n_loc) * DD + c * 4);
    }
  }

  for (int ch = 0; ch < 8; ++ch) {
    __syncthreads();

    // ---- stage K (scaled+masked, split) + diag, from prefetched regs ----
#pragma unroll
    for (int rep = 0; rep < 2; ++rep) {
      const int f = t + rep * 256;
      const int n = f >> 4, dg = f & 15;
      const float msc = pmk[rep] * SCALE;
      float k0 = pk4[rep].x * msc, k1 = pk4[rep].y * msc,
            k2 = pk4[rep].z * msc, k3 = pk4[rep].w * msc;
      float ss = fmaf(k0, k0, fmaf(k1, k1, fmaf(k2, k2, k3 * k3)));
      ss += __shfl_xor(ss, 1); ss += __shfl_xor(ss, 2);
      ss += __shfl_xor(ss, 4); ss += __shfl_xor(ss, 8);
      if (dg == 0) sDiag[n] = 0.5f * ss;
      unsigned h0 = pk2(k0, k1), h1 = pk2(k2, k3);
      float q0 = k0 - hif(k0), q1 = k1 - hif(k1);
      float q2 = k2 - hif(k2), q3 = k3 - hif(k3);
      *(uint2*)(&sK[0][n * 72 + dg * 4]) = make_uint2(h0, h1);
      *(uint2*)(&sK[1][n * 72 + dg * 4]) = make_uint2(pk2(q0, q1), pk2(q2, q3));
    }

    // ---- stage V^T via wave shfl-transpose; accumulate Vs partial ----
#pragma unroll
    for (int rep = 0; rep < 2; ++rep) {
      const int nb = w * 4 + rep * 16;
      const float mk = pmv[rep];
      float4 vv = pv4[rep];
      float va[4] = {vv.x * mk, vv.y * mk, vv.z * mk, vv.w * mk};
      float g[4];
#pragma unroll
      for (int k = 0; k < 4; ++k) {
        const int gi = (sq + k) & 3;
        float sel = va[(sq - k) & 3];
        g[gi] = __shfl(sel, gi * 16 + c);
      }
      const int estar = c * 4 + sq;  // lane's column, rows nb..nb+3
      vsacc += ((g[0] + g[1]) + (g[2] + g[3]));
      unsigned h0 = pk2(g[0], g[1]), h1 = pk2(g[2], g[3]);
      float q0 = g[0] - hif(g[0]), q1 = g[1] - hif(g[1]);
      float q2 = g[2] - hif(g[2]), q3 = g[3] - hif(g[3]);
      *(uint2*)(&sVt[0][estar * 40 + nb]) = make_uint2(h0, h1);
      *(uint2*)(&sVt[1][estar * 40 + nb]) = make_uint2(pk2(q0, q1), pk2(q2, q3));
    }
    __syncthreads();

    // ---- issue next chunk's loads: whole MFMA phase hides the latency ----
    if (ch < 7) {
      const int rb = r0 + (ch + 1) * 32;
#pragma unroll
      for (int rep = 0; rep < 2; ++rep) {
        const int f = t + rep * 256;
        const int n = f >> 4;
        pmk[rep] = mask[b * NN + rb + n];
        pk4[rep] = *(const float4*)(K + ((size_t)bh * NN + rb + n) * DD + (f & 15) * 4);
        const int n_loc = w * 4 + rep * 16 + sq;
        pmv[rep] = mask[b * NN + rb + n_loc];
        pv4[rep] = *(const float4*)(V + ((size_t)bh * NN + rb + n_loc) * DD + c * 4);
      }
    }

    // ---- frags ----
    Frag Ak[2][2][2];
#pragma unroll
    for (int i = 0; i < 2; ++i)
#pragma unroll
      for (int s = 0; s < 2; ++s) {
        Ak[i][s][0].s8 = *(const short8*)&sK[0][(i * 16 + c) * 72 + s * 32 + sq * 8];
        Ak[i][s][1].s8 = *(const short8*)&sK[1][(i * 16 + c) * 72 + s * 32 + sq * 8];
      }
    Frag Bv[4][2];
#pragma unroll
    for (int E = 0; E < 4; ++E) {
      Bv[E][0].s8 = *(const short8*)&sVt[0][(E * 16 + c) * 40 + sq * 8];
      Bv[E][1].s8 = *(const short8*)&sVt[1][(E * 16 + c) * 40 + sq * 8];
    }

#pragma unroll
    for (int tt = 0; tt < 4; ++tt) {
      // S1: xp for both n-tiles
      floatx4 xacc[2];
#pragma unroll
      for (int i = 0; i < 2; ++i) {
        floatx4 a = (floatx4){0.f, 0.f, 0.f, 0.f};
#pragma unroll
        for (int s = 0; s < 2; ++s) {
          a = __builtin_amdgcn_mfma_f32_16x16x32_bf16(Ak[i][s][0].s8, Bp[tt][s][0].s8, a, 0, 0, 0);
          a = __builtin_amdgcn_mfma_f32_16x16x32_bf16(Ak[i][s][0].s8, Bp[tt][s][1].s8, a, 0, 0, 0);
          a = __builtin_amdgcn_mfma_f32_16x16x32_bf16(Ak[i][s][1].s8, Bp[tt][s][0].s8, a, 0, 0, 0);
        }
        xacc[i] = a;
      }
      // S2: exp frame-0, max, ksum, phi scatter (wave-local, swizzled)
      const int qp_c = sq >> 1, half = (sq & 1) * 4;
#pragma unroll
      for (int i = 0; i < 2; ++i) {
        float p[4];
#pragma unroll
        for (int jj = 0; jj < 4; ++jj) {
          float xp = xacc[i][jj];
          mxloc = fmaxf(mxloc, xp);
          p[jj] = __expf(xp - sDiag[i * 16 + sq * 4 + jj]);
          ksac[tt] += p[jj];
        }
        unsigned h0 = pk2(p[0], p[1]), h1 = pk2(p[2], p[3]);
        float q0 = p[0] - hif(p[0]), q1 = p[1] - hif(p[1]);
        float q2 = p[2] - hif(p[2]), q3 = p[3] - hif(p[3]);
        const int tl = (i * 2 + qp_c) * 16 + c;
        const int idx = ph16(tl) * 8 + half;
        *(uint2*)&sPhi[w][0][idx] = make_uint2(h0, h1);
        *(uint2*)&sPhi[w][1][idx] = make_uint2(pk2(q0, q1), pk2(q2, q3));
      }
      // S3: ctx += phi^T @ Vm (wave-local DS ordering: no barrier needed)
      Frag Ap[2];
      Ap[0].s8 = *(const short8*)&sPhi[w][0][ph16(l) * 8];
      Ap[1].s8 = *(const short8*)&sPhi[w][1][ph16(l) * 8];
#pragma unroll
      for (int E = 0; E < 4; ++E) {
        ctxacc[tt][E] = __builtin_amdgcn_mfma_f32_16x16x32_bf16(Ap[0].s8, Bv[E][0].s8, ctxacc[tt][E], 0, 0, 0);
        ctxacc[tt][E] = __builtin_amdgcn_mfma_f32_16x16x32_bf16(Ap[0].s8, Bv[E][1].s8, ctxacc[tt][E], 0, 0, 0);
        ctxacc[tt][E] = __builtin_amdgcn_mfma_f32_16x16x32_bf16(Ap[1].s8, Bv[E][0].s8, ctxacc[tt][E], 0, 0, 0);
      }
    }
  }

  // ---- epilogue: ksum partials, block max, Vs partial, ctx out ----
#pragma unroll
  for (int tt = 0; tt < 4; ++tt) {
    float v = ksac[tt];
    v += __shfl_xor(v, 16);
    v += __shfl_xor(v, 32);
    if (sq == 0) atomicAdd(&ksE[bh * MM + m0 + tt * 16 + c], v);
  }
#pragma unroll
  for (int off = 1; off <= 32; off <<= 1) mxloc = fmaxf(mxloc, __shfl_xor(mxloc, off));
  if (l == 0) sRed[w] = mxloc;
  sVsum[w][c * 4 + sq] = vsacc;
  __syncthreads();
  if (t == 0)
    atomicMaxF(&stabk[bh], fmaxf(fmaxf(sRed[0], sRed[1]), fmaxf(sRed[2], sRed[3])));
  if (t < 64)
    atomicAdd(&Vs[bh * DD + t],
              (sVsum[0][t] + sVsum[1][t]) + (sVsum[2][t] + sVsum[3][t]));

  if (PARTIAL) {
    float* cg = ctxOut + ((size_t)(bh * NCH + blockIdx.x) * MM) * DD;
#pragma unroll
    for (int tt = 0; tt < 4; ++tt)
#pragma unroll
      for (int E = 0; E < 4; ++E)
#pragma unroll
        for (int r = 0; r < 4; ++r)
          cg[(m0 + tt * 16 + sq * 4 + r) * DD + E * 16 + c] = ctxacc[tt][E][r];
  } else {
    float* cg = ctxOut + (size_t)bh * MM * DD;
#pragma unroll
    for (int tt = 0; tt < 4; ++tt)
#pragma unroll
      for (int E = 0; E < 4; ++E)
#pragma unroll
        for (int r = 0; r < 4; ++r)
          atomicAdd(&cg[(m0 + tt * 16 + sq * 4 + r) * DD + E * 16 + c],
                    ctxacc[tt][E][r]);
  }
}

// ---------------- fixup: reduce partials, scale+eps, emit ctxT; ksfin ------
// grid (8 mchunks of 32, 32 bh), 256 thr.
template <int NPARTS>
__global__ __launch_bounds__(256) void fixup_kernel(
    const float* __restrict__ stabk, const float* __restrict__ Vs,
    const float* __restrict__ ksE, const float* __restrict__ ctxParts,
    float* __restrict__ ksum, float* __restrict__ kssum,
    float* __restrict__ ctxsum, unsigned short* __restrict__ ctxTH,
    unsigned short* __restrict__ ctxTL) {
  const int bh = blockIdx.y, mc = blockIdx.x, t = threadIdx.x;
  const float es = __expf(-stabk[bh]);
  const int e = t & 63, g = t >> 6;
  const float vse = EPSI * Vs[bh * DD + e];

  __shared__ float tile[64 * 33];  // [e][ml] ml<32
  __shared__ float cred[256];

  float csum = 0.f;
#pragma unroll
  for (int r = 0; r < 8; ++r) {
    const int ml = r * 4 + g;        // m-local in 32-chunk
    const int m = mc * 32 + ml;
    float x = 0.f;
#pragma unroll
    for (int p = 0; p < NPARTS; ++p)
      x += ctxParts[(((size_t)bh * NPARTS + p) * MM + m) * DD + e];
    float v = RATIO * (es * x + vse);
    csum += v;
    tile[e * 33 + ml] = v;
  }
  cred[t] = csum;
  __syncthreads();
  if (t < 64)
    atomicAdd(&ctxsum[bh * DD + t],
              (cred[t] + cred[t + 64]) + (cred[t + 128] + cred[t + 192]));

  // coalesced transposed write-out
  {
    const int ml5 = t & 31, elg = t >> 5;
#pragma unroll
    for (int r = 0; r < 8; ++r) {
      const int el = r * 8 + elg;
      float v = tile[el * 33 + ml5];
      const size_t o = ((size_t)(bh * DD + el)) * MM + mc * 32 + ml5;
      ctxTH[o] = bhi(v);
      ctxTL[o] = bhi(v - hif(v));
    }
  }

  // ksfin fold (one block column per head)
  if (mc == 0) {
    __syncthreads();
    const float kv = RATIO * (es * ksE[bh * MM + t] + (float)NN * EPSI);
    ksum[bh * MM + t] = kv;
    cred[t] = kv;
    __syncthreads();
    for (int off = 128; off >= 1; off >>= 1) {
      if (t < off) cred[t] += cred[t + off];
      __syncthreads();
    }
    if (t == 0) kssum[bh] = cred[0];
  }
}

// ---------------- out: MFMA Q side + T14 staging prefetch, plain LB --------
__global__ __launch_bounds__(256) void out_kernel(
    const float* __restrict__ Q,
    const unsigned short* __restrict__ projH, const unsigned short* __restrict__ projL,
    const float* __restrict__ ksum,
    const unsigned short* __restrict__ ctxTH, const unsigned short* __restrict__ ctxTL,
    const float* __restrict__ kssum, const float* __restrict__ ctxsum,
    float* __restrict__ out) {
  const int bh = blockIdx.y;
  const int r0 = blockIdx.x * 64;
  const int t = threadIdx.x, w = t >> 6, l = t & 63, c = l & 15, sq = l >> 4;
  const int row = t >> 2, q4 = t & 3;

  __shared__ __align__(16) unsigned short sQ[2][64 * 80];
  __shared__ __align__(16) unsigned short sP[2][64 * 80];
  __shared__ __align__(16) unsigned short sC[2][64 * 80];
  __shared__ float sKs[256];
  __shared__ float sDiag[64];
  __shared__ __align__(16) unsigned short sPhi[4][2][2][512];

  {
    const float* qp = Q + ((size_t)bh * NN + r0 + row) * DD + q4 * 16;
    float4 t0 = *(const float4*)(qp + 0), t1 = *(const float4*)(qp + 4),
           t2 = *(const float4*)(qp + 8), t3 = *(const float4*)(qp + 12);
    float v[16] = {t0.x, t0.y, t0.z, t0.w, t1.x, t1.y, t1.z, t1.w,
                   t2.x, t2.y, t2.z, t2.w, t3.x, t3.y, t3.z, t3.w};
    float ss = 0.f;
#pragma unroll
    for (int j = 0; j < 16; ++j) { v[j] *= SCALE; ss = fmaf(v[j], v[j], ss); }
    ss += __shfl_xor(ss, 1);
    ss += __shfl_xor(ss, 2);
    if (q4 == 0) sDiag[row] = 0.5f * ss;
    unsigned short* dh = &sQ[0][row * 80 + q4 * 16];
    unsigned short* dl = &sQ[1][row * 80 + q4 * 16];
#pragma unroll
    for (int j = 0; j < 8; ++j) {
      *(unsigned*)&dh[2 * j] = pk2(v[2 * j], v[2 * j + 1]);
      float l0 = v[2 * j] - hif(v[2 * j]), l1 = v[2 * j + 1] - hif(v[2 * j + 1]);
      *(unsigned*)&dl[2 * j] = pk2(l0, l1);
    }
  }
  sKs[t] = ksum[bh * MM + t];

  // ---- prime staging prefetch for mc=0 (regs; consumed at loop-top) ----
  uint4 pfP[4], pfC[4];
  {
    const size_t gp = (size_t)(row)*DD + q4 * 16;
    pfP[0] = ((const uint4*)&projH[gp])[0];
    pfP[1] = ((const uint4*)&projH[gp])[1];
    pfP[2] = ((const uint4*)&projL[gp])[0];
    pfP[3] = ((const uint4*)&projL[gp])[1];
    const size_t gc = ((size_t)bh * DD + row) * MM + q4 * 16;
    pfC[0] = ((const uint4*)&ctxTH[gc])[0];
    pfC[1] = ((const uint4*)&ctxTH[gc])[1];
    pfC[2] = ((const uint4*)&ctxTL[gc])[0];
    pfC[3] = ((const uint4*)&ctxTL[gc])[1];
  }
  __syncthreads();

  Frag Bq[2][2];
#pragma unroll
  for (int s = 0; s < 2; ++s)
#pragma unroll
    for (int p = 0; p < 2; ++p)
      Bq[s][p].s8 = *(const short8*)&sQ[p][(w * 16 + c) * 80 + s * 32 + sq * 8];

  const float diagc = sDiag[w * 16 + c];
  floatx4 oacc[4];
#pragma unroll
  for (int E = 0; E < 4; ++E) oacc[E] = (floatx4){0.f, 0.f, 0.f, 0.f};
  float mxacc = NEGINF, dsacc = 0.f;

  for (int mc = 0; mc < 4; ++mc) {
    __syncthreads();
    // ---- write prefetched staging regs to LDS ----
    {
      *(uint4*)&sP[0][row * 80 + q4 * 16] = pfP[0];
      *(uint4*)&sP[0][row * 80 + q4 * 16 + 8] = pfP[1];
      *(uint4*)&sP[1][row * 80 + q4 * 16] = pfP[2];
      *(uint4*)&sP[1][row * 80 + q4 * 16 + 8] = pfP[3];
      *(uint4*)&sC[0][row * 80 + q4 * 16] = pfC[0];
      *(uint4*)&sC[0][row * 80 + q4 * 16 + 8] = pfC[1];
      *(uint4*)&sC[1][row * 80 + q4 * 16] = pfC[2];
      *(uint4*)&sC[1][row * 80 + q4 * 16 + 8] = pfC[3];
    }
    __syncthreads();

    // ---- issue mc+1 staging loads: MFMA phase below hides L2 latency ----
    if (mc < 3) {
      const size_t gp = (size_t)((mc + 1) * 64 + row) * DD + q4 * 16;
      pfP[0] = ((const uint4*)&projH[gp])[0];
      pfP[1] = ((const uint4*)&projH[gp])[1];
      pfP[2] = ((const uint4*)&projL[gp])[0];
      pfP[3] = ((const uint4*)&projL[gp])[1];
      const size_t gc = ((size_t)bh * DD + row) * MM + (mc + 1) * 64 + q4 * 16;
      pfC[0] = ((const uint4*)&ctxTH[gc])[0];
      pfC[1] = ((const uint4*)&ctxTH[gc])[1];
      pfC[2] = ((const uint4*)&ctxTL[gc])[0];
      pfC[3] = ((const uint4*)&ctxTL[gc])[1];
    }

#pragma unroll
    for (int tt = 0; tt < 4; ++tt) {
      Frag Af[2][2];
#pragma unroll
      for (int s = 0; s < 2; ++s)
#pragma unroll
        for (int p = 0; p < 2; ++p)
          Af[s][p].s8 = *(const short8*)&sP[p][(tt * 16 + c) * 80 + s * 32 + sq * 8];
      floatx4 x = (floatx4){0.f, 0.f, 0.f, 0.f};
#pragma unroll
      for (int s = 0; s < 2; ++s) {
        x = __builtin_amdgcn_mfma_f32_16x16x32_bf16(Af[s][0].s8, Bq[s][0].s8, x, 0, 0, 0);
        x = __builtin_amdgcn_mfma_f32_16x16x32_bf16(Af[s][0].s8, Bq[s][1].s8, x, 0, 0, 0);
        x = __builtin_amdgcn_mfma_f32_16x16x32_bf16(Af[s][1].s8, Bq[s][0].s8, x, 0, 0, 0);
      }
      float p4[4];
#pragma unroll
      for (int jj = 0; jj < 4; ++jj) {
        const float xp = x[jj];
        mxacc = fmaxf(mxacc, xp);
        p4[jj] = __expf(xp - diagc);
        dsacc = fmaf(p4[jj], sKs[mc * 64 + tt * 16 + sq * 4 + jj], dsacc);
      }
      const int kstep = tt >> 1;
      const int tl = ((tt & 1) * 2 + (sq >> 1)) * 16 + c;
      const int off = (sq & 1) * 4;
      float l0 = p4[0] - hif(p4[0]), l1 = p4[1] - hif(p4[1]);
      float l2 = p4[2] - hif(p4[2]), l3 = p4[3] - hif(p4[3]);
      *(uint2*)&sPhi[w][0][kstep][tl * 8 + off] = make_uint2(pk2(p4[0], p4[1]), pk2(p4[2], p4[3]));
      *(uint2*)&sPhi[w][1][kstep][tl * 8 + off] = make_uint2(pk2(l0, l1), pk2(l2, l3));
    }

#pragma unroll
    for (int ks = 0; ks < 2; ++ks) {
      Frag Aph[2];
      Aph[0].s8 = *(const short8*)&sPhi[w][0][ks][l * 8];
      Aph[1].s8 = *(const short8*)&sPhi[w][1][ks][l * 8];
#pragma unroll
      for (int E = 0; E < 4; ++E) {
        Frag Bc0, Bc1;
        Bc0.s8 = *(const short8*)&sC[0][(E * 16 + c) * 80 + ks * 32 + sq * 8];
        Bc1.s8 = *(const short8*)&sC[1][(E * 16 + c) * 80 + ks * 32 + sq * 8];
        oacc[E] = __builtin_amdgcn_mfma_f32_16x16x32_bf16(Aph[0].s8, Bc0.s8, oacc[E], 0, 0, 0);
        oacc[E] = __builtin_amdgcn_mfma_f32_16x16x32_bf16(Aph[0].s8, Bc1.s8, oacc[E], 0, 0, 0);
        oacc[E] = __builtin_amdgcn_mfma_f32_16x16x32_bf16(Aph[1].s8, Bc0.s8, oacc[E], 0, 0, 0);
      }
    }
  }

  mxacc = fmaxf(mxacc, __shfl_xor(mxacc, 16));
  mxacc = fmaxf(mxacc, __shfl_xor(mxacc, 32));
  dsacc += __shfl_xor(dsacc, 16);
  dsacc += __shfl_xor(dsacc, 32);

  const float kss = kssum[bh];
  float fac[4], oinv[4];
#pragma unroll
  for (int jj = 0; jj < 4; ++jj) {
    const int src = sq * 4 + jj;
    const float s_row = __shfl(mxacc, src);
    const float d_row = __shfl(dsacc, src);
    const float f = __expf(s_row) * EPSI;
    fac[jj] = f;
    oinv[jj] = 1.f / (d_row + f * kss);
  }

  const float* csb = ctxsum + bh * DD;
#pragma unroll
  for (int E = 0; E < 4; ++E) {
    const float cse = csb[E * 16 + c];
#pragma unroll
    for (int jj = 0; jj < 4; ++jj) {
      const int row2 = r0 + w * 16 + sq * 4 + jj;
      out[((size_t)bh * NN + row2) * DD + E * 16 + c] =
          (oacc[E][jj] + fac[jj] * cse) * oinv[jj];
    }
  }
}

extern "C" void kernel_launch(void* const* d_in, const int* in_sizes, int n_in,
                              void* d_out, int out_size, void* d_ws, size_t ws_size,
                              hipStream_t stream) {
  const float* Q    = (const float*)d_in[0];
  const float* K    = (const float*)d_in[1];
  const float* V    = (const float*)d_in[2];
  const float* mask = (const float*)d_in[3];
  const float* proj = (const float*)d_in[4];
  float* out = (float*)d_out;

  float* wsf = (float*)d_ws;
  float* stabk  = wsf;                          // 32
  float* ksum   = wsf + 32;                     // 8192
  float* kssum  = wsf + 8224;                   // 32
  float* Vs     = wsf + 8256;                   // 2048
  float* ctxsum = wsf + 10304;                  // 2048
  float* ksE    = wsf + 12352;                  // 8192
  unsigned short* projH = (unsigned short*)(wsf + 20544);   // 16384 shorts
  unsigned short* projL = (unsigned short*)(wsf + 28736);   // 16384 shorts
  unsigned short* ctxTH = (unsigned short*)(wsf + 36928);   // 524288 shorts
  unsigned short* ctxTL = (unsigned short*)(wsf + 299072);  // 524288 shorts
  float* ctxBig = wsf + 561216;  // PARTIAL: NCH*32*16384 = 8388608 fl (33.5MB)
                                 // fallback: 524288 fl (ctxE)

  const size_t need_partial = (size_t)(561216 + NCH * BH * MM * DD) * 4;
  const bool partial = ws_size >= need_partial;

  prep_kernel<<<64, 256, 0, stream>>>(proj, projH, projL, stabk, Vs, ctxsum, ksE);

  if (partial) {
    kside_kernel<true><<<dim3(NCH, BH), 256, 0, stream>>>(
        K, V, mask, projH, projL, stabk, ksE, ctxBig, Vs);
    fixup_kernel<NCH><<<dim3(8, BH), 256, 0, stream>>>(
        stabk, Vs, ksE, ctxBig, ksum, kssum, ctxsum, ctxTH, ctxTL);
  } else {
    hipMemsetAsync(ctxBig, 0, (size_t)MM * DD * BH * 4, stream);
    kside_kernel<false><<<dim3(NCH, BH), 256, 0, stream>>>(
        K, V, mask, projH, projL, stabk, ksE, ctxBig, Vs);
    fixup_kernel<1><<<dim3(8, BH), 256, 0, stream>>>(
        stabk, Vs, ksE, ctxBig, ksum, kssum, ctxsum, ctxTH, ctxTL);
  }

  out_kernel<<<dim3(64, BH), 256, 0, stream>>>(
      Q, projH, projL, ksum, ctxTH, ctxTL, kssum, ctxsum, out);
}

// Round 8
// 254.839 us; speedup vs baseline: 1.0919x; 1.0878x over previous
//
#include <hip/hip_runtime.h>
#include <hip/hip_bf16.h>

// Performer (FAVOR+) attention. B=4 H=8 N=4096 D=64 M=256.
// Round-14:
//  - Round-13 post-mortem: register prefetch across barriers spills at ~128
//    VGPR regardless of launch_bounds (r12/r13 identical: 124 VGPR, 180MB
//    WRITE). Register-resident prefetch in out_kernel is a dead end.
//  - out_kernel staging now uses __builtin_amdgcn_global_load_lds (zero data
//    VGPRs -> spill mechanism structurally gone). sP(mc+1) issued after the
//    post-phi barrier (in flight across PV), sC(mc+1) after the post-PV
//    barrier (in flight across next phi). __syncthreads' vmcnt(0) drain
//    lands exactly where consumption starts.
//  - global_load_lds writes linearly (lane x 16B): pads dropped, planes are
//    unpadded [64][64] with XOR chunk swizzle (linear dest + inverse-swz
//    SOURCE + swz READ; phys (row,ch4) holds logical (row, ch4^(row&7));
//    reads use ch4'=(s*4+sq)^(c&7)). 2-way bank aliasing only (free).
//  - LDS 79360 -> ~50.4KB (pads dropped + sPhi overlaid on dead sQ) ->
//    3 blocks/CU (was 2). Extra barrier after Bq protects the overlay.
//  - kside (r11 T14, validated 73us), fixup, prep byte-identical.

typedef __attribute__((ext_vector_type(8))) short short8;
typedef __attribute__((ext_vector_type(4))) float floatx4;

constexpr int BB = 4, HH = 8, NN = 4096, DD = 64, MM = 256, BH = 32;
constexpr int NCH = 16;  // n-chunks per head (kside grid.x)
constexpr float SCALE = 0.3535533905932738f;  // 64^-0.25
constexpr float RATIO = 0.0625f;              // 256^-0.5
constexpr float EPSI  = 1e-4f;
constexpr float NEGINF = -3.4e38f;

#define GLOAD_LDS16(SRC, DST)                                        \
  __builtin_amdgcn_global_load_lds(                                  \
      (const __attribute__((address_space(1))) unsigned int*)(SRC),  \
      (__attribute__((address_space(3))) unsigned int*)(DST), 16, 0, 0)

__device__ inline unsigned pk2(float a, float b) {
  unsigned ua = __float_as_uint(a) + 0x8000u;
  unsigned ub = __float_as_uint(b) + 0x8000u;
  return (ua >> 16) | (ub & 0xffff0000u);
}
__device__ inline float hif(float x) {
  return __uint_as_float((__float_as_uint(x) + 0x8000u) & 0xffff0000u);
}
__device__ inline unsigned short bhi(float x) {
  return (unsigned short)((__float_as_uint(x) + 0x8000u) >> 16);
}
__device__ inline int ph16(int i) { return (i & 56) | ((i + (i >> 3)) & 7); }

union Frag { short8 s8; unsigned u[4]; };

__device__ inline void atomicMaxF(float* a, float v) {
  unsigned* ai = (unsigned*)a;
  unsigned old = __atomic_load_n(ai, __ATOMIC_RELAXED);
  while (__uint_as_float(old) < v) {
    unsigned assumed = old;
    old = atomicCAS(ai, assumed, __float_as_uint(v));
    if (old == assumed) break;
  }
}

// ---------------- prep: split proj; init stabk; zero small accumulators ----
__global__ __launch_bounds__(256) void prep_kernel(
    const float* __restrict__ proj, unsigned short* __restrict__ projH,
    unsigned short* __restrict__ projL, float* __restrict__ stabk,
    float* __restrict__ Vs, float* __restrict__ ctxsum,
    float* __restrict__ ksE) {
  const int i = blockIdx.x * 256 + threadIdx.x;  // 16384 elems
  float v = proj[i];
  projH[i] = bhi(v);
  projL[i] = bhi(v - hif(v));
  if (i < BH) stabk[i] = NEGINF;
  if (i < 2048) { Vs[i] = 0.f; ctxsum[i] = 0.f; }
  if (i < 8192) ksE[i] = 0.f;
}

// ---------------- kside: MFMA phi_k pass (round-11 verbatim) ---------------
// grid (NCH, 32), 256 thr. Block: 256 K-rows, 8 chunks of 32, all 256 feats.
// T14 prefetch: chunk ch+1's K/V loads issued post-staging-barrier.
template <bool PARTIAL>
__global__ __launch_bounds__(256) void kside_kernel(
    const float* __restrict__ K, const float* __restrict__ V,
    const float* __restrict__ mask,
    const unsigned short* __restrict__ projH, const unsigned short* __restrict__ projL,
    float* __restrict__ stabk, float* __restrict__ ksE,
    float* __restrict__ ctxOut, float* __restrict__ Vs) {
  const int bh = blockIdx.y, b = bh >> 3;
  const int t = threadIdx.x;
  const int w = t >> 6, l = t & 63, c = l & 15, sq = l >> 4;
  const int m0 = w * 64;

  __shared__ __align__(16) unsigned short sK[2][32 * 72];   // [plane][n][d] pad 72
  __shared__ __align__(16) unsigned short sVt[2][64 * 40];  // [plane][e][n] pad 40
  __shared__ float sDiag[32];
  __shared__ float sRed[4];
  __shared__ float sVsum[4][64];
  __shared__ __align__(16) unsigned short sPhi[4][2][512];  // [w][plane][swizzled]

  // persistent B-frags of P^T from pre-split planes
  Frag Bp[4][2][2];
#pragma unroll
  for (int tt = 0; tt < 4; ++tt)
#pragma unroll
    for (int s = 0; s < 2; ++s) {
      const size_t o = (size_t)(m0 + tt * 16 + c) * DD + s * 32 + sq * 8;
      Bp[tt][s][0].s8 = *(const short8*)&projH[o];
      Bp[tt][s][1].s8 = *(const short8*)&projL[o];
    }

  floatx4 ctxacc[4][4];
#pragma unroll
  for (int i = 0; i < 4; ++i)
#pragma unroll
    for (int j = 0; j < 4; ++j) ctxacc[i][j] = (floatx4){0.f, 0.f, 0.f, 0.f};
  float ksac[4] = {0.f, 0.f, 0.f, 0.f};
  float mxloc = NEGINF;
  float vsacc = 0.f;  // masked V column-sum partial (column estar = c*4+sq)

  const int r0 = blockIdx.x * 256;

  // ---- prime prefetch for ch=0 ----
  float4 pk4[2], pv4[2];
  float pmk[2], pmv[2];
  {
    const int rb = r0;
#pragma unroll
    for (int rep = 0; rep < 2; ++rep) {
      const int f = t + rep * 256;
      const int n = f >> 4;
      pmk[rep] = mask[b * NN + rb + n];
      pk4[rep] = *(const float4*)(K + ((size_t)bh * NN + rb + n) * DD + (f & 15) * 4);
      const int n_loc = w * 4 + rep * 16 + sq;
      pmv[rep] = mask[b * NN + rb + n_loc];
      pv4[rep] = *(const float4*)(V + ((size_t)bh * NN + rb + n_loc) * DD + c * 4);
    }
  }

  for (int ch = 0; ch < 8; ++ch) {
    __syncthreads();

    // ---- stage K (scaled+masked, split) + diag, from prefetched regs ----
#pragma unroll
    for (int rep = 0; rep < 2; ++rep) {
      const int f = t + rep * 256;
      const int n = f >> 4, dg = f & 15;
      const float msc = pmk[rep] * SCALE;
      float k0 = pk4[rep].x * msc, k1 = pk4[rep].y * msc,
            k2 = pk4[rep].z * msc, k3 = pk4[rep].w * msc;
      float ss = fmaf(k0, k0, fmaf(k1, k1, fmaf(k2, k2, k3 * k3)));
      ss += __shfl_xor(ss, 1); ss += __shfl_xor(ss, 2);
      ss += __shfl_xor(ss, 4); ss += __shfl_xor(ss, 8);
      if (dg == 0) sDiag[n] = 0.5f * ss;
      unsigned h0 = pk2(k0, k1), h1 = pk2(k2, k3);
      float q0 = k0 - hif(k0), q1 = k1 - hif(k1);
      float q2 = k2 - hif(k2), q3 = k3 - hif(k3);
      *(uint2*)(&sK[0][n * 72 + dg * 4]) = make_uint2(h0, h1);
      *(uint2*)(&sK[1][n * 72 + dg * 4]) = make_uint2(pk2(q0, q1), pk2(q2, q3));
    }

    // ---- stage V^T via wave shfl-transpose; accumulate Vs partial ----
#pragma unroll
    for (int rep = 0; rep < 2; ++rep) {
      const int nb = w * 4 + rep * 16;
      const float mk = pmv[rep];
      float4 vv = pv4[rep];
      float va[4] = {vv.x * mk, vv.y * mk, vv.z * mk, vv.w * mk};
      float g[4];
#pragma unroll
      for (int k = 0; k < 4; ++k) {
        const int gi = (sq + k) & 3;
        float sel = va[(sq - k) & 3];
        g[gi] = __shfl(sel, gi * 16 + c);
      }
      const int estar = c * 4 + sq;  // lane's column, rows nb..nb+3
      vsacc += ((g[0] + g[1]) + (g[2] + g[3]));
      unsigned h0 = pk2(g[0], g[1]), h1 = pk2(g[2], g[3]);
      float q0 = g[0] - hif(g[0]), q1 = g[1] - hif(g[1]);
      float q2 = g[2] - hif(g[2]), q3 = g[3] - hif(g[3]);
      *(uint2*)(&sVt[0][estar * 40 + nb]) = make_uint2(h0, h1);
      *(uint2*)(&sVt[1][estar * 40 + nb]) = make_uint2(pk2(q0, q1), pk2(q2, q3));
    }
    __syncthreads();

    // ---- issue next chunk's loads: whole MFMA phase hides the latency ----
    if (ch < 7) {
      const int rb = r0 + (ch + 1) * 32;
#pragma unroll
      for (int rep = 0; rep < 2; ++rep) {
        const int f = t + rep * 256;
        const int n = f >> 4;
        pmk[rep] = mask[b * NN + rb + n];
        pk4[rep] = *(const float4*)(K + ((size_t)bh * NN + rb + n) * DD + (f & 15) * 4);
        const int n_loc = w * 4 + rep * 16 + sq;
        pmv[rep] = mask[b * NN + rb + n_loc];
        pv4[rep] = *(const float4*)(V + ((size_t)bh * NN + rb + n_loc) * DD + c * 4);
      }
    }

    // ---- frags ----
    Frag Ak[2][2][2];
#pragma unroll
    for (int i = 0; i < 2; ++i)
#pragma unroll
      for (int s = 0; s < 2; ++s) {
        Ak[i][s][0].s8 = *(const short8*)&sK[0][(i * 16 + c) * 72 + s * 32 + sq * 8];
        Ak[i][s][1].s8 = *(const short8*)&sK[1][(i * 16 + c) * 72 + s * 32 + sq * 8];
      }
    Frag Bv[4][2];
#pragma unroll
    for (int E = 0; E < 4; ++E) {
      Bv[E][0].s8 = *(const short8*)&sVt[0][(E * 16 + c) * 40 + sq * 8];
      Bv[E][1].s8 = *(const short8*)&sVt[1][(E * 16 + c) * 40 + sq * 8];
    }

#pragma unroll
    for (int tt = 0; tt < 4; ++tt) {
      // S1: xp for both n-tiles
      floatx4 xacc[2];
#pragma unroll
      for (int i = 0; i < 2; ++i) {
        floatx4 a = (floatx4){0.f, 0.f, 0.f, 0.f};
#pragma unroll
        for (int s = 0; s < 2; ++s) {
          a = __builtin_amdgcn_mfma_f32_16x16x32_bf16(Ak[i][s][0].s8, Bp[tt][s][0].s8, a, 0, 0, 0);
          a = __builtin_amdgcn_mfma_f32_16x16x32_bf16(Ak[i][s][0].s8, Bp[tt][s][1].s8, a, 0, 0, 0);
          a = __builtin_amdgcn_mfma_f32_16x16x32_bf16(Ak[i][s][1].s8, Bp[tt][s][0].s8, a, 0, 0, 0);
        }
        xacc[i] = a;
      }
      // S2: exp frame-0, max, ksum, phi scatter (wave-local, swizzled)
      const int qp_c = sq >> 1, half = (sq & 1) * 4;
#pragma unroll
      for (int i = 0; i < 2; ++i) {
        float p[4];
#pragma unroll
        for (int jj = 0; jj < 4; ++jj) {
          float xp = xacc[i][jj];
          mxloc = fmaxf(mxloc, xp);
          p[jj] = __expf(xp - sDiag[i * 16 + sq * 4 + jj]);
          ksac[tt] += p[jj];
        }
        unsigned h0 = pk2(p[0], p[1]), h1 = pk2(p[2], p[3]);
        float q0 = p[0] - hif(p[0]), q1 = p[1] - hif(p[1]);
        float q2 = p[2] - hif(p[2]), q3 = p[3] - hif(p[3]);
        const int tl = (i * 2 + qp_c) * 16 + c;
        const int idx = ph16(tl) * 8 + half;
        *(uint2*)&sPhi[w][0][idx] = make_uint2(h0, h1);
        *(uint2*)&sPhi[w][1][idx] = make_uint2(pk2(q0, q1), pk2(q2, q3));
      }
      // S3: ctx += phi^T @ Vm (wave-local DS ordering: no barrier needed)
      Frag Ap[2];
      Ap[0].s8 = *(const short8*)&sPhi[w][0][ph16(l) * 8];
      Ap[1].s8 = *(const short8*)&sPhi[w][1][ph16(l) * 8];
#pragma unroll
      for (int E = 0; E < 4; ++E) {
        ctxacc[tt][E] = __builtin_amdgcn_mfma_f32_16x16x32_bf16(Ap[0].s8, Bv[E][0].s8, ctxacc[tt][E], 0, 0, 0);
        ctxacc[tt][E] = __builtin_amdgcn_mfma_f32_16x16x32_bf16(Ap[0].s8, Bv[E][1].s8, ctxacc[tt][E], 0, 0, 0);
        ctxacc[tt][E] = __builtin_amdgcn_mfma_f32_16x16x32_bf16(Ap[1].s8, Bv[E][0].s8, ctxacc[tt][E], 0, 0, 0);
      }
    }
  }

  // ---- epilogue: ksum partials, block max, Vs partial, ctx out ----
#pragma unroll
  for (int tt = 0; tt < 4; ++tt) {
    float v = ksac[tt];
    v += __shfl_xor(v, 16);
    v += __shfl_xor(v, 32);
    if (sq == 0) atomicAdd(&ksE[bh * MM + m0 + tt * 16 + c], v);
  }
#pragma unroll
  for (int off = 1; off <= 32; off <<= 1) mxloc = fmaxf(mxloc, __shfl_xor(mxloc, off));
  if (l == 0) sRed[w] = mxloc;
  sVsum[w][c * 4 + sq] = vsacc;
  __syncthreads();
  if (t == 0)
    atomicMaxF(&stabk[bh], fmaxf(fmaxf(sRed[0], sRed[1]), fmaxf(sRed[2], sRed[3])));
  if (t < 64)
    atomicAdd(&Vs[bh * DD + t],
              (sVsum[0][t] + sVsum[1][t]) + (sVsum[2][t] + sVsum[3][t]));

  if (PARTIAL) {
    float* cg = ctxOut + ((size_t)(bh * NCH + blockIdx.x) * MM) * DD;
#pragma unroll
    for (int tt = 0; tt < 4; ++tt)
#pragma unroll
      for (int E = 0; E < 4; ++E)
#pragma unroll
        for (int r = 0; r < 4; ++r)
          cg[(m0 + tt * 16 + sq * 4 + r) * DD + E * 16 + c] = ctxacc[tt][E][r];
  } else {
    float* cg = ctxOut + (size_t)bh * MM * DD;
#pragma unroll
    for (int tt = 0; tt < 4; ++tt)
#pragma unroll
      for (int E = 0; E < 4; ++E)
#pragma unroll
        for (int r = 0; r < 4; ++r)
          atomicAdd(&cg[(m0 + tt * 16 + sq * 4 + r) * DD + E * 16 + c],
                    ctxacc[tt][E][r]);
  }
}

// ---------------- fixup: reduce partials, scale+eps, emit ctxT; ksfin ------
// grid (8 mchunks of 32, 32 bh), 256 thr.
template <int NPARTS>
__global__ __launch_bounds__(256) void fixup_kernel(
    const float* __restrict__ stabk, const float* __restrict__ Vs,
    const float* __restrict__ ksE, const float* __restrict__ ctxParts,
    float* __restrict__ ksum, float* __restrict__ kssum,
    float* __restrict__ ctxsum, unsigned short* __restrict__ ctxTH,
    unsigned short* __restrict__ ctxTL) {
  const int bh = blockIdx.y, mc = blockIdx.x, t = threadIdx.x;
  const float es = __expf(-stabk[bh]);
  const int e = t & 63, g = t >> 6;
  const float vse = EPSI * Vs[bh * DD + e];

  __shared__ float tile[64 * 33];  // [e][ml] ml<32
  __shared__ float cred[256];

  float csum = 0.f;
#pragma unroll
  for (int r = 0; r < 8; ++r) {
    const int ml = r * 4 + g;        // m-local in 32-chunk
    const int m = mc * 32 + ml;
    float x = 0.f;
#pragma unroll
    for (int p = 0; p < NPARTS; ++p)
      x += ctxParts[(((size_t)bh * NPARTS + p) * MM + m) * DD + e];
    float v = RATIO * (es * x + vse);
    csum += v;
    tile[e * 33 + ml] = v;
  }
  cred[t] = csum;
  __syncthreads();
  if (t < 64)
    atomicAdd(&ctxsum[bh * DD + t],
              (cred[t] + cred[t + 64]) + (cred[t + 128] + cred[t + 192]));

  // coalesced transposed write-out
  {
    const int ml5 = t & 31, elg = t >> 5;
#pragma unroll
    for (int r = 0; r < 8; ++r) {
      const int el = r * 8 + elg;
      float v = tile[el * 33 + ml5];
      const size_t o = ((size_t)(bh * DD + el)) * MM + mc * 32 + ml5;
      ctxTH[o] = bhi(v);
      ctxTL[o] = bhi(v - hif(v));
    }
  }

  // ksfin fold (one block column per head)
  if (mc == 0) {
    __syncthreads();
    const float kv = RATIO * (es * ksE[bh * MM + t] + (float)NN * EPSI);
    ksum[bh * MM + t] = kv;
    cred[t] = kv;
    __syncthreads();
    for (int off = 128; off >= 1; off >>= 1) {
      if (t < off) cred[t] += cred[t + off];
      __syncthreads();
    }
    if (t == 0) kssum[bh] = cred[0];
  }
}

// ---------------- out: MFMA Q side, global_load_lds async staging ----------
// Planes sP/sC: unpadded [64 rows][64 shorts] = 512 x 16B chunks, XOR-swz:
// physical chunk (prow,pch4) holds logical (prow, pch4^(prow&7)).
// Reads use ch4' = (s*4+sq)^(c&7). sPhi overlaid on dead sQ. LDS ~50.4KB.
__global__ __launch_bounds__(256) void out_kernel(
    const float* __restrict__ Q,
    const unsigned short* __restrict__ projH, const unsigned short* __restrict__ projL,
    const float* __restrict__ ksum,
    const unsigned short* __restrict__ ctxTH, const unsigned short* __restrict__ ctxTL,
    const float* __restrict__ kssum, const float* __restrict__ ctxsum,
    float* __restrict__ out) {
  const int bh = blockIdx.y;
  const int r0 = blockIdx.x * 64;
  const int t = threadIdx.x, w = t >> 6, l = t & 63, c = l & 15, sq = l >> 4;
  const int row = t >> 2, q4 = t & 3;

  __shared__ __align__(16) unsigned short sQPhi[8192];   // 16KB: sQ then sPhi
  __shared__ __align__(16) unsigned short sP[2][4096];   // 16KB proj tile
  __shared__ __align__(16) unsigned short sC[2][4096];   // 16KB ctxT tile
  __shared__ float sKs[256];
  __shared__ float sDiag[64];
#define SQ_(p, idx) sQPhi[(p) * 4096 + (idx)]
#define SPHI_(wv, p, ks, idx) sQPhi[((((wv) * 2 + (p)) * 2 + (ks)) * 512) + (idx)]

  const unsigned short* ctxH_b = ctxTH + (size_t)bh * DD * MM;
  const unsigned short* ctxL_b = ctxTL + (size_t)bh * DD * MM;

  // DMA-stage one 64x64-short plane (512 chunks), swizzled placement.
  auto stageDMA = [&](const unsigned short* srcBase, int rowStride,
                      unsigned short* plane) {
#pragma unroll
    for (int r2 = 0; r2 < 2; ++r2) {
      const int pc = r2 * 256 + t;
      const int prow = pc >> 3, pch4 = pc & 7;
      const int lch4 = pch4 ^ (prow & 7);
      const unsigned short* src = srcBase + prow * rowStride + lch4 * 8;
      unsigned short* dst = plane + (r2 * 256 + (t & 192)) * 8;  // wave-uniform
      GLOAD_LDS16(src, dst);
    }
  };

  // ---- issue mc=0 staging DMAs first: latency hides under Q staging ----
  stageDMA(projH, DD, &sP[0][0]);
  stageDMA(projL, DD, &sP[1][0]);
  stageDMA(ctxH_b, MM, &sC[0][0]);
  stageDMA(ctxL_b, MM, &sC[1][0]);

  // ---- Q staging: scale, diag, split planes (linear, unpadded 64) ----
  {
    const float* qp = Q + ((size_t)bh * NN + r0 + row) * DD + q4 * 16;
    float4 t0 = *(const float4*)(qp + 0), t1 = *(const float4*)(qp + 4),
           t2 = *(const float4*)(qp + 8), t3 = *(const float4*)(qp + 12);
    float v[16] = {t0.x, t0.y, t0.z, t0.w, t1.x, t1.y, t1.z, t1.w,
                   t2.x, t2.y, t2.z, t2.w, t3.x, t3.y, t3.z, t3.w};
    float ss = 0.f;
#pragma unroll
    for (int j = 0; j < 16; ++j) { v[j] *= SCALE; ss = fmaf(v[j], v[j], ss); }
    ss += __shfl_xor(ss, 1);
    ss += __shfl_xor(ss, 2);
    if (q4 == 0) sDiag[row] = 0.5f * ss;
    unsigned short* dh = &SQ_(0, row * 64 + q4 * 16);
    unsigned short* dl = &SQ_(1, row * 64 + q4 * 16);
#pragma unroll
    for (int j = 0; j < 8; ++j) {
      *(unsigned*)&dh[2 * j] = pk2(v[2 * j], v[2 * j + 1]);
      float l0 = v[2 * j] - hif(v[2 * j]), l1 = v[2 * j + 1] - hif(v[2 * j + 1]);
      *(unsigned*)&dl[2 * j] = pk2(l0, l1);
    }
  }
  sKs[t] = ksum[bh * MM + t];
  __syncthreads();  // B0: drains DMA + sQ/sKs/sDiag writes

  Frag Bq[2][2];
#pragma unroll
  for (int s = 0; s < 2; ++s)
#pragma unroll
    for (int p = 0; p < 2; ++p)
      Bq[s][p].s8 = *(const short8*)&SQ_(p, (w * 16 + c) * 64 + s * 32 + sq * 8);
  const float diagc = sDiag[w * 16 + c];
  __syncthreads();  // B0b: sQ reads complete before sPhi overlay writes

  floatx4 oacc[4];
#pragma unroll
  for (int E = 0; E < 4; ++E) oacc[E] = (floatx4){0.f, 0.f, 0.f, 0.f};
  float mxacc = NEGINF, dsacc = 0.f;

  for (int mc = 0; mc < 4; ++mc) {
    // ---- phi phase: reads sP (swizzled), sKs; writes sPhi (wave-local) ----
#pragma unroll
    for (int tt = 0; tt < 4; ++tt) {
      Frag Af[2][2];
#pragma unroll
      for (int s = 0; s < 2; ++s) {
        const int a = (tt * 16 + c) * 64 + (((s * 4 + sq) ^ (c & 7)) * 8);
        Af[s][0].s8 = *(const short8*)&sP[0][a];
        Af[s][1].s8 = *(const short8*)&sP[1][a];
      }
      floatx4 x = (floatx4){0.f, 0.f, 0.f, 0.f};
#pragma unroll
      for (int s = 0; s < 2; ++s) {
        x = __builtin_amdgcn_mfma_f32_16x16x32_bf16(Af[s][0].s8, Bq[s][0].s8, x, 0, 0, 0);
        x = __builtin_amdgcn_mfma_f32_16x16x32_bf16(Af[s][0].s8, Bq[s][1].s8, x, 0, 0, 0);
        x = __builtin_amdgcn_mfma_f32_16x16x32_bf16(Af[s][1].s8, Bq[s][0].s8, x, 0, 0, 0);
      }
      float p4[4];
#pragma unroll
      for (int jj = 0; jj < 4; ++jj) {
        const float xp = x[jj];
        mxacc = fmaxf(mxacc, xp);
        p4[jj] = __expf(xp - diagc);
        dsacc = fmaf(p4[jj], sKs[mc * 64 + tt * 16 + sq * 4 + jj], dsacc);
      }
      const int kstep = tt >> 1;
      const int tl = ((tt & 1) * 2 + (sq >> 1)) * 16 + c;
      const int off = (sq & 1) * 4;
      float l0 = p4[0] - hif(p4[0]), l1 = p4[1] - hif(p4[1]);
      float l2 = p4[2] - hif(p4[2]), l3 = p4[3] - hif(p4[3]);
      *(uint2*)&SPHI_(w, 0, kstep, tl * 8 + off) = make_uint2(pk2(p4[0], p4[1]), pk2(p4[2], p4[3]));
      *(uint2*)&SPHI_(w, 1, kstep, tl * 8 + off) = make_uint2(pk2(l0, l1), pk2(l2, l3));
    }

    __syncthreads();  // B1: all waves done reading sP(mc)
    if (mc < 3) {     // sP(mc+1) in flight across the PV phase
      stageDMA(projH + (mc + 1) * 64 * DD, DD, &sP[0][0]);
      stageDMA(projL + (mc + 1) * 64 * DD, DD, &sP[1][0]);
    }

    // ---- PV phase: reads sPhi (wave-local) + sC (swizzled) ----
#pragma unroll
    for (int ks = 0; ks < 2; ++ks) {
      Frag Aph[2];
      Aph[0].s8 = *(const short8*)&SPHI_(w, 0, ks, l * 8);
      Aph[1].s8 = *(const short8*)&SPHI_(w, 1, ks, l * 8);
#pragma unroll
      for (int E = 0; E < 4; ++E) {
        const int a = (E * 16 + c) * 64 + (((ks * 4 + sq) ^ (c & 7)) * 8);
        Frag Bc0, Bc1;
        Bc0.s8 = *(const short8*)&sC[0][a];
        Bc1.s8 = *(const short8*)&sC[1][a];
        oacc[E] = __builtin_amdgcn_mfma_f32_16x16x32_bf16(Aph[0].s8, Bc0.s8, oacc[E], 0, 0, 0);
        oacc[E] = __builtin_amdgcn_mfma_f32_16x16x32_bf16(Aph[0].s8, Bc1.s8, oacc[E], 0, 0, 0);
        oacc[E] = __builtin_amdgcn_mfma_f32_16x16x32_bf16(Aph[1].s8, Bc0.s8, oacc[E], 0, 0, 0);
      }
    }

    __syncthreads();  // B2: PV done reading sC(mc); drains sP(mc+1) DMA
    if (mc < 3) {     // sC(mc+1) in flight across the next phi phase
      stageDMA(ctxH_b + (mc + 1) * 64, MM, &sC[0][0]);
      stageDMA(ctxL_b + (mc + 1) * 64, MM, &sC[1][0]);
    }
  }
#undef SQ_
#undef SPHI_

  mxacc = fmaxf(mxacc, __shfl_xor(mxacc, 16));
  mxacc = fmaxf(mxacc, __shfl_xor(mxacc, 32));
  dsacc += __shfl_xor(dsacc, 16);
  dsacc += __shfl_xor(dsacc, 32);

  const float kss = kssum[bh];
  float fac[4], oinv[4];
#pragma unroll
  for (int jj = 0; jj < 4; ++jj) {
    const int src = sq * 4 + jj;
    const float s_row = __shfl(mxacc, src);
    const float d_row = __shfl(dsacc, src);
    const float f = __expf(s_row) * EPSI;
    fac[jj] = f;
    oinv[jj] = 1.f / (d_row + f * kss);
  }

  const float* csb = ctxsum + bh * DD;
#pragma unroll
  for (int E = 0; E < 4; ++E) {
    const float cse = csb[E * 16 + c];
#pragma unroll
    for (int jj = 0; jj < 4; ++jj) {
      const int row2 = r0 + w * 16 + sq * 4 + jj;
      out[((size_t)bh * NN + row2) * DD + E * 16 + c] =
          (oacc[E][jj] + fac[jj] * cse) * oinv[jj];
    }
  }
}

extern "C" void kernel_launch(void* const* d_in, const int* in_sizes, int n_in,
                              void* d_out, int out_size, void* d_ws, size_t ws_size,
                              hipStream_t stream) {
  const float* Q    = (const float*)d_in[0];
  const float* K    = (const float*)d_in[1];
  const float* V    = (const float*)d_in[2];
  const float* mask = (const float*)d_in[3];
  const float* proj = (const float*)d_in[4];
  float* out = (float*)d_out;

  float* wsf = (float*)d_ws;
  float* stabk  = wsf;                          // 32
  float* ksum   = wsf + 32;                     // 8192
  float* kssum  = wsf + 8224;                   // 32
  float* Vs     = wsf + 8256;                   // 2048
  float* ctxsum = wsf + 10304;                  // 2048
  float* ksE    = wsf + 12352;                  // 8192
  unsigned short* projH = (unsigned short*)(wsf + 20544);   // 16384 shorts
  unsigned short* projL = (unsigned short*)(wsf + 28736);   // 16384 shorts
  unsigned short* ctxTH = (unsigned short*)(wsf + 36928);   // 524288 shorts
  unsigned short* ctxTL = (unsigned short*)(wsf + 299072);  // 524288 shorts
  float* ctxBig = wsf + 561216;  // PARTIAL: NCH*32*16384 = 8388608 fl (33.5MB)
                                 // fallback: 524288 fl (ctxE)

  const size_t need_partial = (size_t)(561216 + NCH * BH * MM * DD) * 4;
  const bool partial = ws_size >= need_partial;

  prep_kernel<<<64, 256, 0, stream>>>(proj, projH, projL, stabk, Vs, ctxsum, ksE);

  if (partial) {
    kside_kernel<true><<<dim3(NCH, BH), 256, 0, stream>>>(
        K, V, mask, projH, projL, stabk, ksE, ctxBig, Vs);
    fixup_kernel<NCH><<<dim3(8, BH), 256, 0, stream>>>(
        stabk, Vs, ksE, ctxBig, ksum, kssum, ctxsum, ctxTH, ctxTL);
  } else {
    hipMemsetAsync(ctxBig, 0, (size_t)MM * DD * BH * 4, stream);
    kside_kernel<false><<<dim3(NCH, BH), 256, 0, stream>>>(
        K, V, mask, projH, projL, stabk, ksE, ctxBig, Vs);
    fixup_kernel<1><<<dim3(8, BH), 256, 0, stream>>>(
        stabk, Vs, ksE, ctxBig, ksum, kssum, ctxsum, ctxTH, ctxTL);
  }

  out_kernel<<<dim3(64, BH), 256, 0, stream>>>(
      Q, projH, projL, ksum, ctxTH, ctxTL, kssum, ctxsum, out);
}

// Round 9
// 225.486 us; speedup vs baseline: 1.2340x; 1.1302x over previous
//
#include <hip/hip_runtime.h>
#include <hip/hip_bf16.h>

// Performer (FAVOR+) attention. B=4 H=8 N=4096 D=64 M=256.
// Round-15:
//  - Round-14 post-mortem: DMA+swizzle out (81us) LOST to the r4 LDS-staged
//    out (<73us in r11's profile). All four alternative staging mechanisms
//    for out_kernel measured worse; its bulk-coalesced LDS staging at
//    2 blocks/CU is the empirical optimum of the explored space.
//  - REVERT to exact r11 config (228.1us measured): kside r11-T14 (73us),
//    out r4 LDS-staged (256,2), fixup, prep.
//  - ONE zero-risk addition: T5 s_setprio(1) around MFMA clusters in kside
//    and out. Both run 2 independent blocks/CU with unsynchronized barrier
//    schedules -> one block's waves stage while the other's do MFMA; the
//    priority hint lets MFMA-phase waves win issue arbitration. No VGPR,
//    no layout, no numerics impact. Null case == r11 exactly.

typedef __attribute__((ext_vector_type(8))) short short8;
typedef __attribute__((ext_vector_type(4))) float floatx4;

constexpr int BB = 4, HH = 8, NN = 4096, DD = 64, MM = 256, BH = 32;
constexpr int NCH = 16;  // n-chunks per head (kside grid.x)
constexpr float SCALE = 0.3535533905932738f;  // 64^-0.25
constexpr float RATIO = 0.0625f;              // 256^-0.5
constexpr float EPSI  = 1e-4f;
constexpr float NEGINF = -3.4e38f;

__device__ inline unsigned pk2(float a, float b) {
  unsigned ua = __float_as_uint(a) + 0x8000u;
  unsigned ub = __float_as_uint(b) + 0x8000u;
  return (ua >> 16) | (ub & 0xffff0000u);
}
__device__ inline float hif(float x) {
  return __uint_as_float((__float_as_uint(x) + 0x8000u) & 0xffff0000u);
}
__device__ inline unsigned short bhi(float x) {
  return (unsigned short)((__float_as_uint(x) + 0x8000u) >> 16);
}
__device__ inline int ph16(int i) { return (i & 56) | ((i + (i >> 3)) & 7); }

union Frag { short8 s8; unsigned u[4]; };

__device__ inline void atomicMaxF(float* a, float v) {
  unsigned* ai = (unsigned*)a;
  unsigned old = __atomic_load_n(ai, __ATOMIC_RELAXED);
  while (__uint_as_float(old) < v) {
    unsigned assumed = old;
    old = atomicCAS(ai, assumed, __float_as_uint(v));
    if (old == assumed) break;
  }
}

// ---------------- prep: split proj; init stabk; zero small accumulators ----
__global__ __launch_bounds__(256) void prep_kernel(
    const float* __restrict__ proj, unsigned short* __restrict__ projH,
    unsigned short* __restrict__ projL, float* __restrict__ stabk,
    float* __restrict__ Vs, float* __restrict__ ctxsum,
    float* __restrict__ ksE) {
  const int i = blockIdx.x * 256 + threadIdx.x;  // 16384 elems
  float v = proj[i];
  projH[i] = bhi(v);
  projL[i] = bhi(v - hif(v));
  if (i < BH) stabk[i] = NEGINF;
  if (i < 2048) { Vs[i] = 0.f; ctxsum[i] = 0.f; }
  if (i < 8192) ksE[i] = 0.f;
}

// ---------------- kside: MFMA phi_k pass (r11 + setprio) -------------------
// grid (NCH, 32), 256 thr. Block: 256 K-rows, 8 chunks of 32, all 256 feats.
// T14 prefetch: chunk ch+1's K/V loads issued post-staging-barrier.
template <bool PARTIAL>
__global__ __launch_bounds__(256) void kside_kernel(
    const float* __restrict__ K, const float* __restrict__ V,
    const float* __restrict__ mask,
    const unsigned short* __restrict__ projH, const unsigned short* __restrict__ projL,
    float* __restrict__ stabk, float* __restrict__ ksE,
    float* __restrict__ ctxOut, float* __restrict__ Vs) {
  const int bh = blockIdx.y, b = bh >> 3;
  const int t = threadIdx.x;
  const int w = t >> 6, l = t & 63, c = l & 15, sq = l >> 4;
  const int m0 = w * 64;

  __shared__ __align__(16) unsigned short sK[2][32 * 72];   // [plane][n][d] pad 72
  __shared__ __align__(16) unsigned short sVt[2][64 * 40];  // [plane][e][n] pad 40
  __shared__ float sDiag[32];
  __shared__ float sRed[4];
  __shared__ float sVsum[4][64];
  __shared__ __align__(16) unsigned short sPhi[4][2][512];  // [w][plane][swizzled]

  // persistent B-frags of P^T from pre-split planes
  Frag Bp[4][2][2];
#pragma unroll
  for (int tt = 0; tt < 4; ++tt)
#pragma unroll
    for (int s = 0; s < 2; ++s) {
      const size_t o = (size_t)(m0 + tt * 16 + c) * DD + s * 32 + sq * 8;
      Bp[tt][s][0].s8 = *(const short8*)&projH[o];
      Bp[tt][s][1].s8 = *(const short8*)&projL[o];
    }

  floatx4 ctxacc[4][4];
#pragma unroll
  for (int i = 0; i < 4; ++i)
#pragma unroll
    for (int j = 0; j < 4; ++j) ctxacc[i][j] = (floatx4){0.f, 0.f, 0.f, 0.f};
  float ksac[4] = {0.f, 0.f, 0.f, 0.f};
  float mxloc = NEGINF;
  float vsacc = 0.f;  // masked V column-sum partial (column estar = c*4+sq)

  const int r0 = blockIdx.x * 256;

  // ---- prime prefetch for ch=0 ----
  float4 pk4[2], pv4[2];
  float pmk[2], pmv[2];
  {
    const int rb = r0;
#pragma unroll
    for (int rep = 0; rep < 2; ++rep) {
      const int f = t + rep * 256;
      const int n = f >> 4;
      pmk[rep] = mask[b * NN + rb + n];
      pk4[rep] = *(const float4*)(K + ((size_t)bh * NN + rb + n) * DD + (f & 15) * 4);
      const int n_loc = w * 4 + rep * 16 + sq;
      pmv[rep] = mask[b * NN + rb + n_loc];
      pv4[rep] = *(const float4*)(V + ((size_t)bh * NN + rb + n_loc) * DD + c * 4);
    }
  }

  for (int ch = 0; ch < 8; ++ch) {
    __syncthreads();

    // ---- stage K (scaled+masked, split) + diag, from prefetched regs ----
#pragma unroll
    for (int rep = 0; rep < 2; ++rep) {
      const int f = t + rep * 256;
      const int n = f >> 4, dg = f & 15;
      const float msc = pmk[rep] * SCALE;
      float k0 = pk4[rep].x * msc, k1 = pk4[rep].y * msc,
            k2 = pk4[rep].z * msc, k3 = pk4[rep].w * msc;
      float ss = fmaf(k0, k0, fmaf(k1, k1, fmaf(k2, k2, k3 * k3)));
      ss += __shfl_xor(ss, 1); ss += __shfl_xor(ss, 2);
      ss += __shfl_xor(ss, 4); ss += __shfl_xor(ss, 8);
      if (dg == 0) sDiag[n] = 0.5f * ss;
      unsigned h0 = pk2(k0, k1), h1 = pk2(k2, k3);
      float q0 = k0 - hif(k0), q1 = k1 - hif(k1);
      float q2 = k2 - hif(k2), q3 = k3 - hif(k3);
      *(uint2*)(&sK[0][n * 72 + dg * 4]) = make_uint2(h0, h1);
      *(uint2*)(&sK[1][n * 72 + dg * 4]) = make_uint2(pk2(q0, q1), pk2(q2, q3));
    }

    // ---- stage V^T via wave shfl-transpose; accumulate Vs partial ----
#pragma unroll
    for (int rep = 0; rep < 2; ++rep) {
      const int nb = w * 4 + rep * 16;
      const float mk = pmv[rep];
      float4 vv = pv4[rep];
      float va[4] = {vv.x * mk, vv.y * mk, vv.z * mk, vv.w * mk};
      float g[4];
#pragma unroll
      for (int k = 0; k < 4; ++k) {
        const int gi = (sq + k) & 3;
        float sel = va[(sq - k) & 3];
        g[gi] = __shfl(sel, gi * 16 + c);
      }
      const int estar = c * 4 + sq;  // lane's column, rows nb..nb+3
      vsacc += ((g[0] + g[1]) + (g[2] + g[3]));
      unsigned h0 = pk2(g[0], g[1]), h1 = pk2(g[2], g[3]);
      float q0 = g[0] - hif(g[0]), q1 = g[1] - hif(g[1]);
      float q2 = g[2] - hif(g[2]), q3 = g[3] - hif(g[3]);
      *(uint2*)(&sVt[0][estar * 40 + nb]) = make_uint2(h0, h1);
      *(uint2*)(&sVt[1][estar * 40 + nb]) = make_uint2(pk2(q0, q1), pk2(q2, q3));
    }
    __syncthreads();

    // ---- issue next chunk's loads: whole MFMA phase hides the latency ----
    if (ch < 7) {
      const int rb = r0 + (ch + 1) * 32;
#pragma unroll
      for (int rep = 0; rep < 2; ++rep) {
        const int f = t + rep * 256;
        const int n = f >> 4;
        pmk[rep] = mask[b * NN + rb + n];
        pk4[rep] = *(const float4*)(K + ((size_t)bh * NN + rb + n) * DD + (f & 15) * 4);
        const int n_loc = w * 4 + rep * 16 + sq;
        pmv[rep] = mask[b * NN + rb + n_loc];
        pv4[rep] = *(const float4*)(V + ((size_t)bh * NN + rb + n_loc) * DD + c * 4);
      }
    }

    // ---- frags ----
    Frag Ak[2][2][2];
#pragma unroll
    for (int i = 0; i < 2; ++i)
#pragma unroll
      for (int s = 0; s < 2; ++s) {
        Ak[i][s][0].s8 = *(const short8*)&sK[0][(i * 16 + c) * 72 + s * 32 + sq * 8];
        Ak[i][s][1].s8 = *(const short8*)&sK[1][(i * 16 + c) * 72 + s * 32 + sq * 8];
      }
    Frag Bv[4][2];
#pragma unroll
    for (int E = 0; E < 4; ++E) {
      Bv[E][0].s8 = *(const short8*)&sVt[0][(E * 16 + c) * 40 + sq * 8];
      Bv[E][1].s8 = *(const short8*)&sVt[1][(E * 16 + c) * 40 + sq * 8];
    }

    __builtin_amdgcn_s_setprio(1);
#pragma unroll
    for (int tt = 0; tt < 4; ++tt) {
      // S1: xp for both n-tiles
      floatx4 xacc[2];
#pragma unroll
      for (int i = 0; i < 2; ++i) {
        floatx4 a = (floatx4){0.f, 0.f, 0.f, 0.f};
#pragma unroll
        for (int s = 0; s < 2; ++s) {
          a = __builtin_amdgcn_mfma_f32_16x16x32_bf16(Ak[i][s][0].s8, Bp[tt][s][0].s8, a, 0, 0, 0);
          a = __builtin_amdgcn_mfma_f32_16x16x32_bf16(Ak[i][s][0].s8, Bp[tt][s][1].s8, a, 0, 0, 0);
          a = __builtin_amdgcn_mfma_f32_16x16x32_bf16(Ak[i][s][1].s8, Bp[tt][s][0].s8, a, 0, 0, 0);
        }
        xacc[i] = a;
      }
      // S2: exp frame-0, max, ksum, phi scatter (wave-local, swizzled)
      const int qp_c = sq >> 1, half = (sq & 1) * 4;
#pragma unroll
      for (int i = 0; i < 2; ++i) {
        float p[4];
#pragma unroll
        for (int jj = 0; jj < 4; ++jj) {
          float xp = xacc[i][jj];
          mxloc = fmaxf(mxloc, xp);
          p[jj] = __expf(xp - sDiag[i * 16 + sq * 4 + jj]);
          ksac[tt] += p[jj];
        }
        unsigned h0 = pk2(p[0], p[1]), h1 = pk2(p[2], p[3]);
        float q0 = p[0] - hif(p[0]), q1 = p[1] - hif(p[1]);
        float q2 = p[2] - hif(p[2]), q3 = p[3] - hif(p[3]);
        const int tl = (i * 2 + qp_c) * 16 + c;
        const int idx = ph16(tl) * 8 + half;
        *(uint2*)&sPhi[w][0][idx] = make_uint2(h0, h1);
        *(uint2*)&sPhi[w][1][idx] = make_uint2(pk2(q0, q1), pk2(q2, q3));
      }
      // S3: ctx += phi^T @ Vm (wave-local DS ordering: no barrier needed)
      Frag Ap[2];
      Ap[0].s8 = *(const short8*)&sPhi[w][0][ph16(l) * 8];
      Ap[1].s8 = *(const short8*)&sPhi[w][1][ph16(l) * 8];
#pragma unroll
      for (int E = 0; E < 4; ++E) {
        ctxacc[tt][E] = __builtin_amdgcn_mfma_f32_16x16x32_bf16(Ap[0].s8, Bv[E][0].s8, ctxacc[tt][E], 0, 0, 0);
        ctxacc[tt][E] = __builtin_amdgcn_mfma_f32_16x16x32_bf16(Ap[0].s8, Bv[E][1].s8, ctxacc[tt][E], 0, 0, 0);
        ctxacc[tt][E] = __builtin_amdgcn_mfma_f32_16x16x32_bf16(Ap[1].s8, Bv[E][0].s8, ctxacc[tt][E], 0, 0, 0);
      }
    }
    __builtin_amdgcn_s_setprio(0);
  }

  // ---- epilogue: ksum partials, block max, Vs partial, ctx out ----
#pragma unroll
  for (int tt = 0; tt < 4; ++tt) {
    float v = ksac[tt];
    v += __shfl_xor(v, 16);
    v += __shfl_xor(v, 32);
    if (sq == 0) atomicAdd(&ksE[bh * MM + m0 + tt * 16 + c], v);
  }
#pragma unroll
  for (int off = 1; off <= 32; off <<= 1) mxloc = fmaxf(mxloc, __shfl_xor(mxloc, off));
  if (l == 0) sRed[w] = mxloc;
  sVsum[w][c * 4 + sq] = vsacc;
  __syncthreads();
  if (t == 0)
    atomicMaxF(&stabk[bh], fmaxf(fmaxf(sRed[0], sRed[1]), fmaxf(sRed[2], sRed[3])));
  if (t < 64)
    atomicAdd(&Vs[bh * DD + t],
              (sVsum[0][t] + sVsum[1][t]) + (sVsum[2][t] + sVsum[3][t]));

  if (PARTIAL) {
    float* cg = ctxOut + ((size_t)(bh * NCH + blockIdx.x) * MM) * DD;
#pragma unroll
    for (int tt = 0; tt < 4; ++tt)
#pragma unroll
      for (int E = 0; E < 4; ++E)
#pragma unroll
        for (int r = 0; r < 4; ++r)
          cg[(m0 + tt * 16 + sq * 4 + r) * DD + E * 16 + c] = ctxacc[tt][E][r];
  } else {
    float* cg = ctxOut + (size_t)bh * MM * DD;
#pragma unroll
    for (int tt = 0; tt < 4; ++tt)
#pragma unroll
      for (int E = 0; E < 4; ++E)
#pragma unroll
        for (int r = 0; r < 4; ++r)
          atomicAdd(&cg[(m0 + tt * 16 + sq * 4 + r) * DD + E * 16 + c],
                    ctxacc[tt][E][r]);
  }
}

// ---------------- fixup: reduce partials, scale+eps, emit ctxT; ksfin ------
// grid (8 mchunks of 32, 32 bh), 256 thr.
template <int NPARTS>
__global__ __launch_bounds__(256) void fixup_kernel(
    const float* __restrict__ stabk, const float* __restrict__ Vs,
    const float* __restrict__ ksE, const float* __restrict__ ctxParts,
    float* __restrict__ ksum, float* __restrict__ kssum,
    float* __restrict__ ctxsum, unsigned short* __restrict__ ctxTH,
    unsigned short* __restrict__ ctxTL) {
  const int bh = blockIdx.y, mc = blockIdx.x, t = threadIdx.x;
  const float es = __expf(-stabk[bh]);
  const int e = t & 63, g = t >> 6;
  const float vse = EPSI * Vs[bh * DD + e];

  __shared__ float tile[64 * 33];  // [e][ml] ml<32
  __shared__ float cred[256];

  float csum = 0.f;
#pragma unroll
  for (int r = 0; r < 8; ++r) {
    const int ml = r * 4 + g;        // m-local in 32-chunk
    const int m = mc * 32 + ml;
    float x = 0.f;
#pragma unroll
    for (int p = 0; p < NPARTS; ++p)
      x += ctxParts[(((size_t)bh * NPARTS + p) * MM + m) * DD + e];
    float v = RATIO * (es * x + vse);
    csum += v;
    tile[e * 33 + ml] = v;
  }
  cred[t] = csum;
  __syncthreads();
  if (t < 64)
    atomicAdd(&ctxsum[bh * DD + t],
              (cred[t] + cred[t + 64]) + (cred[t + 128] + cred[t + 192]));

  // coalesced transposed write-out
  {
    const int ml5 = t & 31, elg = t >> 5;
#pragma unroll
    for (int r = 0; r < 8; ++r) {
      const int el = r * 8 + elg;
      float v = tile[el * 33 + ml5];
      const size_t o = ((size_t)(bh * DD + el)) * MM + mc * 32 + ml5;
      ctxTH[o] = bhi(v);
      ctxTL[o] = bhi(v - hif(v));
    }
  }

  // ksfin fold (one block column per head)
  if (mc == 0) {
    __syncthreads();
    const float kv = RATIO * (es * ksE[bh * MM + t] + (float)NN * EPSI);
    ksum[bh * MM + t] = kv;
    cred[t] = kv;
    __syncthreads();
    for (int off = 128; off >= 1; off >>= 1) {
      if (t < off) cred[t] += cred[t + off];
      __syncthreads();
    }
    if (t == 0) kssum[bh] = cred[0];
  }
}

// ---------------- out: MFMA Q side (round-4 verbatim + setprio) ------------
__global__ __launch_bounds__(256, 2) void out_kernel(
    const float* __restrict__ Q,
    const unsigned short* __restrict__ projH, const unsigned short* __restrict__ projL,
    const float* __restrict__ ksum,
    const unsigned short* __restrict__ ctxTH, const unsigned short* __restrict__ ctxTL,
    const float* __restrict__ kssum, const float* __restrict__ ctxsum,
    float* __restrict__ out) {
  const int bh = blockIdx.y;
  const int r0 = blockIdx.x * 64;
  const int t = threadIdx.x, w = t >> 6, l = t & 63, c = l & 15, sq = l >> 4;

  __shared__ __align__(16) unsigned short sQ[2][64 * 80];
  __shared__ __align__(16) unsigned short sP[2][64 * 80];
  __shared__ __align__(16) unsigned short sC[2][64 * 80];
  __shared__ float sKs[256];
  __shared__ float sDiag[64];
  __shared__ __align__(16) unsigned short sPhi[4][2][2][512];

  {
    const int row = t >> 2, q4 = t & 3;
    const float* qp = Q + ((size_t)bh * NN + r0 + row) * DD + q4 * 16;
    float4 t0 = *(const float4*)(qp + 0), t1 = *(const float4*)(qp + 4),
           t2 = *(const float4*)(qp + 8), t3 = *(const float4*)(qp + 12);
    float v[16] = {t0.x, t0.y, t0.z, t0.w, t1.x, t1.y, t1.z, t1.w,
                   t2.x, t2.y, t2.z, t2.w, t3.x, t3.y, t3.z, t3.w};
    float ss = 0.f;
#pragma unroll
    for (int j = 0; j < 16; ++j) { v[j] *= SCALE; ss = fmaf(v[j], v[j], ss); }
    ss += __shfl_xor(ss, 1);
    ss += __shfl_xor(ss, 2);
    if (q4 == 0) sDiag[row] = 0.5f * ss;
    unsigned short* dh = &sQ[0][row * 80 + q4 * 16];
    unsigned short* dl = &sQ[1][row * 80 + q4 * 16];
#pragma unroll
    for (int j = 0; j < 8; ++j) {
      *(unsigned*)&dh[2 * j] = pk2(v[2 * j], v[2 * j + 1]);
      float l0 = v[2 * j] - hif(v[2 * j]), l1 = v[2 * j + 1] - hif(v[2 * j + 1]);
      *(unsigned*)&dl[2 * j] = pk2(l0, l1);
    }
  }
  sKs[t] = ksum[bh * MM + t];
  __syncthreads();

  Frag Bq[2][2];
#pragma unroll
  for (int s = 0; s < 2; ++s)
#pragma unroll
    for (int p = 0; p < 2; ++p)
      Bq[s][p].s8 = *(const short8*)&sQ[p][(w * 16 + c) * 80 + s * 32 + sq * 8];

  const float diagc = sDiag[w * 16 + c];
  floatx4 oacc[4];
#pragma unroll
  for (int E = 0; E < 4; ++E) oacc[E] = (floatx4){0.f, 0.f, 0.f, 0.f};
  float mxacc = NEGINF, dsacc = 0.f;

  for (int mc = 0; mc < 4; ++mc) {
    __syncthreads();
    {
      const int row = t >> 2, q4 = t & 3;
      const size_t gp = (size_t)(mc * 64 + row) * DD + q4 * 16;
      const uint4* ph = (const uint4*)&projH[gp];
      const uint4* pl = (const uint4*)&projL[gp];
      *(uint4*)&sP[0][row * 80 + q4 * 16] = ph[0];
      *(uint4*)&sP[0][row * 80 + q4 * 16 + 8] = ph[1];
      *(uint4*)&sP[1][row * 80 + q4 * 16] = pl[0];
      *(uint4*)&sP[1][row * 80 + q4 * 16 + 8] = pl[1];
      const size_t gc = ((size_t)bh * DD + row) * MM + mc * 64 + q4 * 16;
      const uint4* chh = (const uint4*)&ctxTH[gc];
      const uint4* cll = (const uint4*)&ctxTL[gc];
      *(uint4*)&sC[0][row * 80 + q4 * 16] = chh[0];
      *(uint4*)&sC[0][row * 80 + q4 * 16 + 8] = chh[1];
      *(uint4*)&sC[1][row * 80 + q4 * 16] = cll[0];
      *(uint4*)&sC[1][row * 80 + q4 * 16 + 8] = cll[1];
    }
    __syncthreads();

    __builtin_amdgcn_s_setprio(1);
#pragma unroll
    for (int tt = 0; tt < 4; ++tt) {
      Frag Af[2][2];
#pragma unroll
      for (int s = 0; s < 2; ++s)
#pragma unroll
        for (int p = 0; p < 2; ++p)
          Af[s][p].s8 = *(const short8*)&sP[p][(tt * 16 + c) * 80 + s * 32 + sq * 8];
      floatx4 x = (floatx4){0.f, 0.f, 0.f, 0.f};
#pragma unroll
      for (int s = 0; s < 2; ++s) {
        x = __builtin_amdgcn_mfma_f32_16x16x32_bf16(Af[s][0].s8, Bq[s][0].s8, x, 0, 0, 0);
        x = __builtin_amdgcn_mfma_f32_16x16x32_bf16(Af[s][0].s8, Bq[s][1].s8, x, 0, 0, 0);
        x = __builtin_amdgcn_mfma_f32_16x16x32_bf16(Af[s][1].s8, Bq[s][0].s8, x, 0, 0, 0);
      }
      float p4[4];
#pragma unroll
      for (int jj = 0; jj < 4; ++jj) {
        const float xp = x[jj];
        mxacc = fmaxf(mxacc, xp);
        p4[jj] = __expf(xp - diagc);
        dsacc = fmaf(p4[jj], sKs[mc * 64 + tt * 16 + sq * 4 + jj], dsacc);
      }
      const int kstep = tt >> 1;
      const int tl = ((tt & 1) * 2 + (sq >> 1)) * 16 + c;
      const int off = (sq & 1) * 4;
      float l0 = p4[0] - hif(p4[0]), l1 = p4[1] - hif(p4[1]);
      float l2 = p4[2] - hif(p4[2]), l3 = p4[3] - hif(p4[3]);
      *(uint2*)&sPhi[w][0][kstep][tl * 8 + off] = make_uint2(pk2(p4[0], p4[1]), pk2(p4[2], p4[3]));
      *(uint2*)&sPhi[w][1][kstep][tl * 8 + off] = make_uint2(pk2(l0, l1), pk2(l2, l3));
    }

#pragma unroll
    for (int ks = 0; ks < 2; ++ks) {
      Frag Aph[2];
      Aph[0].s8 = *(const short8*)&sPhi[w][0][ks][l * 8];
      Aph[1].s8 = *(const short8*)&sPhi[w][1][ks][l * 8];
#pragma unroll
      for (int E = 0; E < 4; ++E) {
        Frag Bc0, Bc1;
        Bc0.s8 = *(const short8*)&sC[0][(E * 16 + c) * 80 + ks * 32 + sq * 8];
        Bc1.s8 = *(const short8*)&sC[1][(E * 16 + c) * 80 + ks * 32 + sq * 8];
        oacc[E] = __builtin_amdgcn_mfma_f32_16x16x32_bf16(Aph[0].s8, Bc0.s8, oacc[E], 0, 0, 0);
        oacc[E] = __builtin_amdgcn_mfma_f32_16x16x32_bf16(Aph[0].s8, Bc1.s8, oacc[E], 0, 0, 0);
        oacc[E] = __builtin_amdgcn_mfma_f32_16x16x32_bf16(Aph[1].s8, Bc0.s8, oacc[E], 0, 0, 0);
      }
    }
    __builtin_amdgcn_s_setprio(0);
  }

  mxacc = fmaxf(mxacc, __shfl_xor(mxacc, 16));
  mxacc = fmaxf(mxacc, __shfl_xor(mxacc, 32));
  dsacc += __shfl_xor(dsacc, 16);
  dsacc += __shfl_xor(dsacc, 32);

  const float kss = kssum[bh];
  float fac[4], oinv[4];
#pragma unroll
  for (int jj = 0; jj < 4; ++jj) {
    const int src = sq * 4 + jj;
    const float s_row = __shfl(mxacc, src);
    const float d_row = __shfl(dsacc, src);
    const float f = __expf(s_row) * EPSI;
    fac[jj] = f;
    oinv[jj] = 1.f / (d_row + f * kss);
  }

  const float* csb = ctxsum + bh * DD;
#pragma unroll
  for (int E = 0; E < 4; ++E) {
    const float cse = csb[E * 16 + c];
#pragma unroll
    for (int jj = 0; jj < 4; ++jj) {
      const int row = r0 + w * 16 + sq * 4 + jj;
      out[((size_t)bh * NN + row) * DD + E * 16 + c] =
          (oacc[E][jj] + fac[jj] * cse) * oinv[jj];
    }
  }
}

extern "C" void kernel_launch(void* const* d_in, const int* in_sizes, int n_in,
                              void* d_out, int out_size, void* d_ws, size_t ws_size,
                              hipStream_t stream) {
  const float* Q    = (const float*)d_in[0];
  const float* K    = (const float*)d_in[1];
  const float* V    = (const float*)d_in[2];
  const float* mask = (const float*)d_in[3];
  const float* proj = (const float*)d_in[4];
  float* out = (float*)d_out;

  float* wsf = (float*)d_ws;
  float* stabk  = wsf;                          // 32
  float* ksum   = wsf + 32;                     // 8192
  float* kssum  = wsf + 8224;                   // 32
  float* Vs     = wsf + 8256;                   // 2048
  float* ctxsum = wsf + 10304;                  // 2048
  float* ksE    = wsf + 12352;                  // 8192
  unsigned short* projH = (unsigned short*)(wsf + 20544);   // 16384 shorts
  unsigned short* projL = (unsigned short*)(wsf + 28736);   // 16384 shorts
  unsigned short* ctxTH = (unsigned short*)(wsf + 36928);   // 524288 shorts
  unsigned short* ctxTL = (unsigned short*)(wsf + 299072);  // 524288 shorts
  float* ctxBig = wsf + 561216;  // PARTIAL: NCH*32*16384 = 8388608 fl (33.5MB)
                                 // fallback: 524288 fl (ctxE)

  const size_t need_partial = (size_t)(561216 + NCH * BH * MM * DD) * 4;
  const bool partial = ws_size >= need_partial;

  prep_kernel<<<64, 256, 0, stream>>>(proj, projH, projL, stabk, Vs, ctxsum, ksE);

  if (partial) {
    kside_kernel<true><<<dim3(NCH, BH), 256, 0, stream>>>(
        K, V, mask, projH, projL, stabk, ksE, ctxBig, Vs);
    fixup_kernel<NCH><<<dim3(8, BH), 256, 0, stream>>>(
        stabk, Vs, ksE, ctxBig, ksum, kssum, ctxsum, ctxTH, ctxTL);
  } else {
    hipMemsetAsync(ctxBig, 0, (size_t)MM * DD * BH * 4, stream);
    kside_kernel<false><<<dim3(NCH, BH), 256, 0, stream>>>(
        K, V, mask, projH, projL, stabk, ksE, ctxBig, Vs);
    fixup_kernel<1><<<dim3(8, BH), 256, 0, stream>>>(
        stabk, Vs, ksE, ctxBig, ksum, kssum, ctxsum, ctxTH, ctxTL);
  }

  out_kernel<<<dim3(64, BH), 256, 0, stream>>>(
      Q, projH, projL, ksum, ctxTH, ctxTL, kssum, ctxsum, out);
}